// Round 6
// baseline (900.141 us; speedup 1.0000x reference)
//
#include <hip/hip_runtime.h>
#include <math.h>

// Problem dims
#define B_   48
#define W_   88
#define C_   256
#define H_   32
#define F_   1024
#define BW_  (B_ * W_)        // 4224
#define BWH_ (B_ * W_ * H_)   // 135168
#define HW_  (H_ * W_)        // 2816

typedef float  f32x4  __attribute__((ext_vector_type(4)));
typedef __bf16 bf16x8 __attribute__((ext_vector_type(8)));

__device__ __forceinline__ unsigned short f2bf(float f) {
  union { float f; unsigned int u; } v; v.f = f;
  unsigned int r = v.u + 0x7FFFu + ((v.u >> 16) & 1u);  // RNE
  return (unsigned short)(r >> 16);
}
__device__ __forceinline__ float bf2f(unsigned short h) {
  union { unsigned int u; float f; } v; v.u = ((unsigned int)h) << 16;
  return v.f;
}
__device__ __forceinline__ unsigned int pack2(float a, float b) {
  return (unsigned int)f2bf(a) | ((unsigned int)f2bf(b) << 16);
}

// ---------------------------------------------------------------------------
// prep_all: every weight-prep step in ONE launch.
//  blk [0,768)      : 32x32 LDS tile transposes f32[in,out] -> bf16[out,in]
//  blk [768,1280)   : Mqk build
//  blk [1280,1792)  : Mvp build
//  blk 1792         : bvp + bqkvs concat
//  blk 1793         : spe[j] = sum_c pe, spe2
//  blk [1794,6018)  : LN(pooled) -> qn_c
// ---------------------------------------------------------------------------
__global__ __launch_bounds__(256) void prep_all(
    const float* __restrict__ Wq_s, const float* __restrict__ Wk_s,
    const float* __restrict__ Wv_s, const float* __restrict__ Wp_s,
    const float* __restrict__ W1, const float* __restrict__ W2,
    const float* __restrict__ Wq_c, const float* __restrict__ Wk_c,
    const float* __restrict__ Wv_c, const float* __restrict__ Wp_c,
    const float* __restrict__ bq_s, const float* __restrict__ bv_s,
    const float* __restrict__ bq_c, const float* __restrict__ bv_c,
    const float* __restrict__ bp_c,
    const float* __restrict__ pooled, const float* __restrict__ cross_pe,
    const float* __restrict__ ln_qc_g, const float* __restrict__ ln_qc_b,
    unsigned short* __restrict__ wqkvs, unsigned short* __restrict__ wps,
    unsigned short* __restrict__ w1t, unsigned short* __restrict__ w2t,
    unsigned short* __restrict__ mqk, unsigned short* __restrict__ mvp,
    float* __restrict__ bqk, float* __restrict__ bvp,
    float* __restrict__ bqkvs, float* __restrict__ spe,
    unsigned short* __restrict__ qn_c) {
  __shared__ float smem[256 * 33 + 4 * 33];
  int blk = blockIdx.x, t = threadIdx.x;

  if (blk < 768) {
    const float* src; unsigned short* dst; int Cc, R, tile;
    if (blk < 64)       { src = Wq_s; dst = wqkvs;          Cc = 256;  R = 256;  tile = blk; }
    else if (blk < 128) { src = Wk_s; dst = wqkvs + 65536;  Cc = 256;  R = 256;  tile = blk - 64; }
    else if (blk < 192) { src = Wv_s; dst = wqkvs + 131072; Cc = 256;  R = 256;  tile = blk - 128; }
    else if (blk < 256) { src = Wp_s; dst = wps;            Cc = 256;  R = 256;  tile = blk - 192; }
    else if (blk < 512) { src = W1;   dst = w1t;            Cc = 1024; R = 256;  tile = blk - 256; }
    else                { src = W2;   dst = w2t;            Cc = 256;  R = 1024; tile = blk - 512; }
    int tcn = Cc >> 5;
    int tr = tile / tcn, tc = tile % tcn;
    float (*lds)[33] = (float(*)[33])smem;
    int r = t >> 3, c4 = (t & 7) * 4;
    float4 v = *(const float4*)(src + (size_t)(tr * 32 + r) * Cc + tc * 32 + c4);
    lds[r][c4 + 0] = v.x; lds[r][c4 + 1] = v.y; lds[r][c4 + 2] = v.z; lds[r][c4 + 3] = v.w;
    __syncthreads();
    int rd = t >> 3, cd4 = (t & 7) * 4;
    uint2 u;
    u.x = pack2(lds[cd4 + 0][rd], lds[cd4 + 1][rd]);
    u.y = pack2(lds[cd4 + 2][rd], lds[cd4 + 3][rd]);
    *(uint2*)(dst + (size_t)(tc * 32 + rd) * R + tr * 32 + cd4) = u;
  } else if (blk < 1280) {
    int lb = blk - 768;
    int h = lb >> 6, cb = lb & 63;
    float (*wq)[33] = (float(*)[33])smem;
    float (*wk)[33] = (float(*)[33])(smem + 256 * 33);
#pragma unroll
    for (int p = 0; p < 8; p++) {
      int dp = (t >> 3) + 32 * p, d4 = (t & 7) * 4;
      float4 v = *(const float4*)(Wq_c + (size_t)dp * 256 + 32 * h + d4);
      wq[dp][d4 + 0] = v.x; wq[dp][d4 + 1] = v.y; wq[dp][d4 + 2] = v.z; wq[dp][d4 + 3] = v.w;
    }
    if (t < 128) {
      int c_l = t >> 5, dd = t & 31;
      wk[c_l][dd] = Wk_c[(size_t)(cb * 4 + c_l) * 256 + 32 * h + dd];
    }
    __syncthreads();
    const float scale = 0.17677669529663689f;
    int c_l = t >> 6, ln = t & 63;
    int n = 256 * h + cb * 4 + c_l;
#pragma unroll
    for (int j = 0; j < 4; j++) {
      int dp = ln + 64 * j;
      float acc = 0.f;
#pragma unroll
      for (int dd = 0; dd < 32; dd++) acc += wq[dp][dd] * wk[c_l][dd];
      mqk[(size_t)n * 256 + dp] = f2bf(acc * scale);
    }
    if (ln == 0) {
      float bb = 0.f;
#pragma unroll
      for (int dd = 0; dd < 32; dd++) bb += bq_c[32 * h + dd] * wk[c_l][dd];
      bqk[n] = bb * scale;
    }
  } else if (blk < 1792) {
    int lb = blk - 1280;
    int h = lb >> 6, db = lb & 63;
    float (*wv)[33] = (float(*)[33])smem;
    float (*wp)[33] = (float(*)[33])(smem + 256 * 33);
#pragma unroll
    for (int p = 0; p < 8; p++) {
      int c = (t >> 3) + 32 * p, d4 = (t & 7) * 4;
      float4 v = *(const float4*)(Wv_c + (size_t)c * 256 + 32 * h + d4);
      wv[c][d4 + 0] = v.x; wv[c][d4 + 1] = v.y; wv[c][d4 + 2] = v.z; wv[c][d4 + 3] = v.w;
    }
    if (t < 128) {
      int d_l = t >> 5, dd = t & 31;
      wp[d_l][dd] = Wp_c[(size_t)(32 * h + dd) * 256 + db * 4 + d_l];
    }
    __syncthreads();
    int d_l = t >> 6, ln = t & 63;
    int d = db * 4 + d_l;
#pragma unroll
    for (int j = 0; j < 4; j++) {
      int c = ln + 64 * j;
      float acc = 0.f;
#pragma unroll
      for (int dd = 0; dd < 32; dd++) acc += wv[c][dd] * wp[d_l][dd];
      mvp[(size_t)d * 2048 + 256 * h + c] = f2bf(acc);
    }
  } else if (blk == 1792) {
    float acc = bp_c[t];
    for (int dp = 0; dp < 256; dp++) acc += bv_c[dp] * Wp_c[(size_t)dp * 256 + t];
    bvp[t] = acc;
    bqkvs[t] = bq_s[t]; bqkvs[256 + t] = 0.f; bqkvs[512 + t] = bv_s[t];
  } else if (blk == 1793) {
    // spe[j] = sum_c pe[j,c]; spe[32+j] = sum_c pe^2
    int j = t >> 3, cp = t & 7;
    float sp = 0.f, sp2 = 0.f;
    for (int i = 0; i < 32; i++) {
      float v = cross_pe[j * 256 + cp * 32 + i];
      sp += v; sp2 += v * v;
    }
    smem[j * 8 + cp] = sp; smem[256 + j * 8 + cp] = sp2;
    __syncthreads();
    if (t < 32) {
      float a = 0.f, a2 = 0.f;
      for (int i = 0; i < 8; i++) { a += smem[t * 8 + i]; a2 += smem[256 + t * 8 + i]; }
      spe[t] = a; spe[32 + t] = a2;
    }
  } else {
    int row = blk - 1794, c = t;
    float v = pooled[(size_t)row * C_ + c];
    float s1 = v, s2 = v * v;
#pragma unroll
    for (int m = 32; m > 0; m >>= 1) {
      s1 += __shfl_xor(s1, m, 64); s2 += __shfl_xor(s2, m, 64);
    }
    float* red = smem;
    int wave = c >> 6;
    if ((c & 63) == 0) { red[wave] = s1; red[4 + wave] = s2; }
    __syncthreads();
    s1 = red[0] + red[1] + red[2] + red[3];
    s2 = red[4] + red[5] + red[6] + red[7];
    float mu = s1 * (1.f / C_);
    float rs = rsqrtf(s2 * (1.f / C_) - mu * mu + 1e-5f);
    qn_c[(size_t)row * C_ + c] = f2bf((v - mu) * rs * ln_qc_g[c] + ln_qc_b[c]);
  }
}

// ---------------------------------------------------------------------------
// xattn_score (K1): block=(b, c-chunk of 16), 768 blocks, 704 threads (w,head).
// Reads features coalesced; accumulates A1+A2[w,head,j] = sum_c gk*q~ *(kv+pe)
// and raw-kv moments per (j,w). Double-buffered j-quarter staging in LDS.
// ---------------------------------------------------------------------------
__global__ __launch_bounds__(704) void xattn_score(
    const float* __restrict__ features, const unsigned short* __restrict__ qt,
    const float* __restrict__ gk, const float* __restrict__ cross_pe,
    float* __restrict__ part1, float* __restrict__ pstat) {
  int b = blockIdx.x >> 4, ch = blockIdx.x & 15, c0 = ch * 16;
  __shared__ unsigned short kvl[2][16 * 8 * 88];
  __shared__ float pel[32][16];
  int t = threadIdx.x, w = t >> 3, head = t & 7;
  if (t < 512) {
    int j = t >> 4, c = t & 15;
    pel[j][c] = cross_pe[j * 256 + c0 + c];
  }
  float gq[16];
  {
    const unsigned short* qrow = qt + (size_t)(b * 88 + w) * 2048 + head * 256 + c0;
#pragma unroll
    for (int c = 0; c < 16; c++) gq[c] = gk[c0 + c] * bf2f(qrow[c]);
  }
  float a1[32];
#pragma unroll
  for (int i = 0; i < 32; i++) a1[i] = 0.f;

  const float* fbase = features + (size_t)(b * 256 + c0) * HW_;
  float4 rg[4];
  int iA[4];
  auto loadq = [&](int q) {
#pragma unroll
    for (int k = 0; k < 4; k++) {
      int p4 = t + k * 704;
      int c = p4 / 176, r = p4 - c * 176;
      int j8 = r / 22, w4 = (r - j8 * 22) * 4;
      iA[k] = (c * 8 + j8) * 88 + w4;
      rg[k] = *(const float4*)(fbase + (size_t)c * HW_ + (q * 8 + j8) * 88 + w4);
    }
  };
  auto storeq = [&](int buf) {
#pragma unroll
    for (int k = 0; k < 4; k++) {
      uint2 u;
      u.x = pack2(rg[k].x, rg[k].y);
      u.y = pack2(rg[k].z, rg[k].w);
      *(uint2*)&kvl[buf][iA[k]] = u;
    }
  };
  loadq(0); storeq(0);
  __syncthreads();
#pragma unroll
  for (int q = 0; q < 4; q++) {
    int cur = q & 1, jb = q * 8;
    if (q < 3) loadq(q + 1);
    const unsigned short* kb = kvl[cur];
#pragma unroll
    for (int c = 0; c < 16; c++) {
      float g = gq[c];
      const unsigned short* row = kb + c * 8 * 88 + w;
#pragma unroll
      for (int j8 = 0; j8 < 8; j8++)
        a1[jb + j8] += g * (bf2f(row[j8 * 88]) + pel[jb + j8][c]);
    }
    {
      int jg = jb + head;
      float s1 = 0.f, s2 = 0.f, cr = 0.f;
#pragma unroll
      for (int c = 0; c < 16; c++) {
        float v = bf2f(kb[(c * 8 + head) * 88 + w]);
        s1 += v; s2 += v * v; cr += v * pel[jg][c];
      }
      size_t sb = (size_t)(b * 16 + ch) * 3 * 2816 + jg * 88 + w;
      pstat[sb] = s1; pstat[sb + 2816] = s2; pstat[sb + 5632] = cr;
    }
    if (q < 3) storeq(cur ^ 1);
    __syncthreads();
  }
  float* dst = part1 + (size_t)((b * 16 + ch) * 88 + w) * 256 + head * 32;
#pragma unroll
  for (int i = 0; i < 32; i += 4) {
    float4 v; v.x = a1[i]; v.y = a1[i + 1]; v.z = a1[i + 2]; v.w = a1[i + 3];
    *(float4*)(dst + i) = v;
  }
}

// ---------------------------------------------------------------------------
// xattn_sm (K2): block per (b,w). Reduce chunk partials, LN algebra, softmax.
// Writes pr[bw][head][j] = p*rs_v and s2a[bw][head] = sum_j p*rs*mu.
// ---------------------------------------------------------------------------
__global__ __launch_bounds__(256) void xattn_sm(
    const float* __restrict__ part1, const float* __restrict__ pstat,
    const unsigned short* __restrict__ qt, const float* __restrict__ spe,
    const float* __restrict__ gk, const float* __restrict__ bk,
    float* __restrict__ pr, float* __restrict__ s2a) {
  int bw = blockIdx.x, b = bw / 88, w = bw - b * 88;
  int t = threadIdx.x, head = t >> 5, j = t & 31;
  __shared__ float statl[3][32];
  float a1 = 0.f;
  for (int ch = 0; ch < 16; ch++)
    a1 += part1[(size_t)((b * 16 + ch) * 88 + w) * 256 + t];
  if (t < 96) {
    int s = t >> 5, jj = t & 31;
    float v = 0.f;
    for (int ch = 0; ch < 16; ch++)
      v += pstat[(size_t)(b * 16 + ch) * 3 * 2816 + s * 2816 + jj * 88 + w];
    statl[s][jj] = v;
  }
  __syncthreads();
  float s1 = statl[0][j], s2v = statl[1][j], cr = statl[2][j];
  float mu  = s1 * (1.f / 256.f);
  float rs  = rsqrtf(s2v * (1.f / 256.f) - mu * mu + 1e-5f);
  float muk = (s1 + spe[j]) * (1.f / 256.f);
  float rsk = rsqrtf((s2v + 2.f * cr + spe[32 + j]) * (1.f / 256.f) - muk * muk + 1e-5f);
  // A3 = sum_c bk*q~, A4 = sum_c gk*q~ (per head) via per-lane partials
  float a3 = 0.f, a4 = 0.f;
  {
    const unsigned short* qrow = qt + (size_t)bw * 2048 + head * 256 + j * 8;
#pragma unroll
    for (int i = 0; i < 8; i++) {
      int c = j * 8 + i;
      float qv = bf2f(qrow[i]);
      a3 += bk[c] * qv; a4 += gk[c] * qv;
    }
  }
#pragma unroll
  for (int m = 16; m > 0; m >>= 1) { a3 += __shfl_xor(a3, m, 32); a4 += __shfl_xor(a4, m, 32); }
  float s = rsk * a1 + a3 - muk * rsk * a4;
  float mx = s;
#pragma unroll
  for (int m = 16; m > 0; m >>= 1) mx = fmaxf(mx, __shfl_xor(mx, m, 32));
  float e = __expf(s - mx);
  float sum = e;
#pragma unroll
  for (int m = 16; m > 0; m >>= 1) sum += __shfl_xor(sum, m, 32);
  float p = e / sum;
  pr[((size_t)bw * 8 + head) * 32 + j] = p * rs;
  float sp = p * rs * mu;
#pragma unroll
  for (int m = 16; m > 0; m >>= 1) sp += __shfl_xor(sp, m, 32);
  if (j == 0) s2a[(size_t)bw * 8 + head] = sp;
}

// ---------------------------------------------------------------------------
// xattn_ctx (K3): block=(b, c-chunk 16). Second features pass weighted by pr.
// ctx[bw][head*256+c] = gv[c]*(sum_j pr*kv - S2) + bv[c]   (bf16)
// ---------------------------------------------------------------------------
__global__ __launch_bounds__(704) void xattn_ctx(
    const float* __restrict__ features, const float* __restrict__ pr,
    const float* __restrict__ s2a, const float* __restrict__ gv,
    const float* __restrict__ bvv, unsigned short* __restrict__ ctx) {
  int b = blockIdx.x >> 4, ch = blockIdx.x & 15, c0 = ch * 16;
  __shared__ unsigned short kvl[2][16 * 8 * 88];
  int t = threadIdx.x, w = t >> 3, head = t & 7;
  float prr[32];
  {
    const float* p = pr + ((size_t)(b * 88 + w) * 8 + head) * 32;
#pragma unroll
    for (int i = 0; i < 32; i += 4) {
      float4 v = *(const float4*)(p + i);
      prr[i] = v.x; prr[i + 1] = v.y; prr[i + 2] = v.z; prr[i + 3] = v.w;
    }
  }
  float S2 = s2a[(size_t)(b * 88 + w) * 8 + head];
  float U[16];
#pragma unroll
  for (int i = 0; i < 16; i++) U[i] = 0.f;

  const float* fbase = features + (size_t)(b * 256 + c0) * HW_;
  float4 rg[4];
  int iA[4];
  auto loadq = [&](int q) {
#pragma unroll
    for (int k = 0; k < 4; k++) {
      int p4 = t + k * 704;
      int c = p4 / 176, r = p4 - c * 176;
      int j8 = r / 22, w4 = (r - j8 * 22) * 4;
      iA[k] = (c * 8 + j8) * 88 + w4;
      rg[k] = *(const float4*)(fbase + (size_t)c * HW_ + (q * 8 + j8) * 88 + w4);
    }
  };
  auto storeq = [&](int buf) {
#pragma unroll
    for (int k = 0; k < 4; k++) {
      uint2 u;
      u.x = pack2(rg[k].x, rg[k].y);
      u.y = pack2(rg[k].z, rg[k].w);
      *(uint2*)&kvl[buf][iA[k]] = u;
    }
  };
  loadq(0); storeq(0);
  __syncthreads();
#pragma unroll
  for (int q = 0; q < 4; q++) {
    int cur = q & 1, jb = q * 8;
    if (q < 3) loadq(q + 1);
    const unsigned short* kb = kvl[cur];
#pragma unroll
    for (int c = 0; c < 16; c++) {
      const unsigned short* row = kb + c * 8 * 88 + w;
      float acc = U[c];
#pragma unroll
      for (int j8 = 0; j8 < 8; j8++)
        acc += prr[jb + j8] * bf2f(row[j8 * 88]);
      U[c] = acc;
    }
    if (q < 3) storeq(cur ^ 1);
    __syncthreads();
  }
  unsigned short* orow = ctx + (size_t)(b * 88 + w) * 2048 + head * 256 + c0;
  unsigned short pk[16];
#pragma unroll
  for (int i = 0; i < 16; i++)
    pk[i] = f2bf(gv[c0 + i] * (U[i] - S2) + bvv[c0 + i]);
  *(uint4*)(orow) = *(uint4*)pk;
  *(uint4*)(orow + 8) = *(uint4*)(pk + 8);
}

// ---------------------------------------------------------------------------
// Row LayerNorm: x f32 [rows, C_] -> bf16 out
// ---------------------------------------------------------------------------
__global__ __launch_bounds__(256) void ln_rows(
    const float* __restrict__ x,
    const float* __restrict__ g, const float* __restrict__ bta,
    unsigned short* __restrict__ out) {
  int row = blockIdx.x, c = threadIdx.x;
  float v = x[(size_t)row * C_ + c];
  float s1 = v, s2 = v * v;
#pragma unroll
  for (int m = 32; m > 0; m >>= 1) {
    s1 += __shfl_xor(s1, m, 64);
    s2 += __shfl_xor(s2, m, 64);
  }
  __shared__ float red[8];
  int wave = c >> 6;
  if ((c & 63) == 0) { red[wave] = s1; red[4 + wave] = s2; }
  __syncthreads();
  s1 = red[0] + red[1] + red[2] + red[3];
  s2 = red[4] + red[5] + red[6] + red[7];
  float mu = s1 * (1.f / C_);
  float rs = rsqrtf(s2 * (1.f / C_) - mu * mu + 1e-5f);
  out[(size_t)row * C_ + c] = f2bf((v - mu) * rs * g[c] + bta[c]);
}

// ---------------------------------------------------------------------------
// ln_dual: out1 = LN(x+pe)*g1+b1, out2 = LN(x)*g2+b2. One read of x.
// ---------------------------------------------------------------------------
__global__ __launch_bounds__(256) void ln_dual(
    const float* __restrict__ x, const float* __restrict__ pe,
    const float* __restrict__ g1, const float* __restrict__ b1a,
    const float* __restrict__ g2, const float* __restrict__ b2a,
    unsigned short* __restrict__ out1, unsigned short* __restrict__ out2) {
  int row = blockIdx.x, c = threadIdx.x;
  float v = x[(size_t)row * C_ + c];
  float vp = v + pe[(size_t)(row % 88) * C_ + c];
  float s1 = v, s2 = v * v, t1 = vp, t2 = vp * vp;
#pragma unroll
  for (int m = 32; m > 0; m >>= 1) {
    s1 += __shfl_xor(s1, m, 64); s2 += __shfl_xor(s2, m, 64);
    t1 += __shfl_xor(t1, m, 64); t2 += __shfl_xor(t2, m, 64);
  }
  __shared__ float red[16];
  int wave = c >> 6;
  if ((c & 63) == 0) {
    red[wave] = s1; red[4 + wave] = s2; red[8 + wave] = t1; red[12 + wave] = t2;
  }
  __syncthreads();
  s1 = red[0] + red[1] + red[2] + red[3];
  s2 = red[4] + red[5] + red[6] + red[7];
  t1 = red[8] + red[9] + red[10] + red[11];
  t2 = red[12] + red[13] + red[14] + red[15];
  float mu = s1 * (1.f / C_), rs = rsqrtf(s2 * (1.f / C_) - mu * mu + 1e-5f);
  float mup = t1 * (1.f / C_), rsp = rsqrtf(t2 * (1.f / C_) - mup * mup + 1e-5f);
  out1[(size_t)row * C_ + c] = f2bf((vp - mup) * rsp * g1[c] + b1a[c]);
  out2[(size_t)row * C_ + c] = f2bf((v - mu) * rs * g2[c] + b2a[c]);
}

// ---------------------------------------------------------------------------
// GEMM: out[M,N] = A[M,K](bf16) @ Bt[N,K](bf16)^T, fp32 acc, reg double-buffer.
// ---------------------------------------------------------------------------
__global__ __launch_bounds__(256) void gemm_bt(
    const unsigned short* __restrict__ A, const unsigned short* __restrict__ Bt,
    int M, int N, int K,
    const float* __restrict__ bias, const float* __restrict__ resid,
    float* __restrict__ outF, unsigned short* __restrict__ outB, int act_gelu) {
  __shared__ __attribute__((aligned(16))) unsigned short As[64][32];
  __shared__ __attribute__((aligned(16))) unsigned short Bs[64][32];
  const int tiles_n = N >> 6;
  const int bm = blockIdx.x / tiles_n;
  const int bn = blockIdx.x % tiles_n;
  const int tid = threadIdx.x;
  const int wave = tid >> 6, lane = tid & 63;
  const int quad = lane >> 4, lr = lane & 15;
  const int wm = (wave >> 1) << 5, wn = (wave & 1) << 5;
  const int lrow = tid >> 2;
  const int lcol = (tid & 3) << 3;
  const size_t a_base = (size_t)(bm * 64 + lrow) * K + lcol;
  const size_t b_base = (size_t)(bn * 64 + lrow) * K + lcol;
  f32x4 acc[2][2] = {};
  uint4 areg = *(const uint4*)(A + a_base);
  uint4 breg = *(const uint4*)(Bt + b_base);
  for (int k0 = 0; k0 < K; k0 += 32) {
    *(uint4*)&As[lrow][lcol] = areg;
    *(uint4*)&Bs[lrow][lcol] = breg;
    __syncthreads();
    if (k0 + 32 < K) {
      areg = *(const uint4*)(A + a_base + k0 + 32);
      breg = *(const uint4*)(Bt + b_base + k0 + 32);
    }
    bf16x8 af0 = *(const bf16x8*)&As[wm + lr][quad << 3];
    bf16x8 af1 = *(const bf16x8*)&As[wm + 16 + lr][quad << 3];
    bf16x8 bf0 = *(const bf16x8*)&Bs[wn + lr][quad << 3];
    bf16x8 bf1 = *(const bf16x8*)&Bs[wn + 16 + lr][quad << 3];
    acc[0][0] = __builtin_amdgcn_mfma_f32_16x16x32_bf16(af0, bf0, acc[0][0], 0, 0, 0);
    acc[0][1] = __builtin_amdgcn_mfma_f32_16x16x32_bf16(af0, bf1, acc[0][1], 0, 0, 0);
    acc[1][0] = __builtin_amdgcn_mfma_f32_16x16x32_bf16(af1, bf0, acc[1][0], 0, 0, 0);
    acc[1][1] = __builtin_amdgcn_mfma_f32_16x16x32_bf16(af1, bf1, acc[1][1], 0, 0, 0);
    __syncthreads();
  }
#pragma unroll
  for (int i = 0; i < 2; i++)
#pragma unroll
    for (int j = 0; j < 2; j++)
#pragma unroll
      for (int rr = 0; rr < 4; rr++) {
        int row = bm * 64 + wm + i * 16 + quad * 4 + rr;
        int col = bn * 64 + wn + j * 16 + lr;
        float val = acc[i][j][rr];
        if (bias) val += bias[col];
        if (act_gelu) val = 0.5f * val * (1.f + erff(val * 0.70710678118654752f));
        if (resid) val += resid[(size_t)row * N + col];
        if (outF) outF[(size_t)row * N + col] = val;
        else outB[(size_t)row * N + col] = f2bf(val);
      }
}

// ---------------------------------------------------------------------------
// gemm_bt_st: like gemm_bt but writes f32 with row stride ldc (+bias).
// ---------------------------------------------------------------------------
__global__ __launch_bounds__(256) void gemm_bt_st(
    const unsigned short* __restrict__ A, const unsigned short* __restrict__ Bt,
    int M, int N, int K, int ldc,
    const float* __restrict__ bias, float* __restrict__ outF) {
  __shared__ __attribute__((aligned(16))) unsigned short As[64][32];
  __shared__ __attribute__((aligned(16))) unsigned short Bs[64][32];
  const int tiles_n = N >> 6;
  const int bm = blockIdx.x / tiles_n;
  const int bn = blockIdx.x % tiles_n;
  const int tid = threadIdx.x;
  const int wave = tid >> 6, lane = tid & 63;
  const int quad = lane >> 4, lr = lane & 15;
  const int wm = (wave >> 1) << 5, wn = (wave & 1) << 5;
  const int lrow = tid >> 2;
  const int lcol = (tid & 3) << 3;
  const size_t a_base = (size_t)(bm * 64 + lrow) * K + lcol;
  const size_t b_base = (size_t)(bn * 64 + lrow) * K + lcol;
  f32x4 acc[2][2] = {};
  uint4 areg = *(const uint4*)(A + a_base);
  uint4 breg = *(const uint4*)(Bt + b_base);
  for (int k0 = 0; k0 < K; k0 += 32) {
    *(uint4*)&As[lrow][lcol] = areg;
    *(uint4*)&Bs[lrow][lcol] = breg;
    __syncthreads();
    if (k0 + 32 < K) {
      areg = *(const uint4*)(A + a_base + k0 + 32);
      breg = *(const uint4*)(Bt + b_base + k0 + 32);
    }
    bf16x8 af0 = *(const bf16x8*)&As[wm + lr][quad << 3];
    bf16x8 af1 = *(const bf16x8*)&As[wm + 16 + lr][quad << 3];
    bf16x8 bf0 = *(const bf16x8*)&Bs[wn + lr][quad << 3];
    bf16x8 bf1 = *(const bf16x8*)&Bs[wn + 16 + lr][quad << 3];
    acc[0][0] = __builtin_amdgcn_mfma_f32_16x16x32_bf16(af0, bf0, acc[0][0], 0, 0, 0);
    acc[0][1] = __builtin_amdgcn_mfma_f32_16x16x32_bf16(af0, bf1, acc[0][1], 0, 0, 0);
    acc[1][0] = __builtin_amdgcn_mfma_f32_16x16x32_bf16(af1, bf0, acc[1][0], 0, 0, 0);
    acc[1][1] = __builtin_amdgcn_mfma_f32_16x16x32_bf16(af1, bf1, acc[1][1], 0, 0, 0);
    __syncthreads();
  }
#pragma unroll
  for (int i = 0; i < 2; i++)
#pragma unroll
    for (int j = 0; j < 2; j++)
#pragma unroll
      for (int rr = 0; rr < 4; rr++) {
        int row = bm * 64 + wm + i * 16 + quad * 4 + rr;
        int col = bn * 64 + wn + j * 16 + lr;
        outF[(size_t)row * ldc + col] = acc[i][j][rr] + bias[col];
      }
}

// ---------------------------------------------------------------------------
// self_attn3: block=(b,h), 192 threads: pair (r=t>>1, dh=t&1) per query row.
// ---------------------------------------------------------------------------
__global__ __launch_bounds__(192) void self_attn3(
    const float* __restrict__ qkv, unsigned short* __restrict__ out) {
  int b = blockIdx.x >> 3;
  int h = blockIdx.x & 7;
  int t = threadIdx.x;
  __shared__ float kl[88][33];
  __shared__ float vl[88][33];
  for (int i = t; i < 704; i += 192) {
    int m = i >> 3, d4 = (i & 7) << 2;
    float4 kv4 = *(const float4*)(qkv + (size_t)(b * 88 + m) * 768 + 256 + h * 32 + d4);
    float4 vv4 = *(const float4*)(qkv + (size_t)(b * 88 + m) * 768 + 512 + h * 32 + d4);
    kl[m][d4 + 0] = kv4.x; kl[m][d4 + 1] = kv4.y; kl[m][d4 + 2] = kv4.z; kl[m][d4 + 3] = kv4.w;
    vl[m][d4 + 0] = vv4.x; vl[m][d4 + 1] = vv4.y; vl[m][d4 + 2] = vv4.z; vl[m][d4 + 3] = vv4.w;
  }
  __syncthreads();
  int r = t >> 1, dh = t & 1;
  if (r < 88) {
    const float* qrow = qkv + (size_t)(b * 88 + r) * 768 + h * 32;
    float qr[32];
#pragma unroll
    for (int g = 0; g < 8; g++) {
      float4 q4 = *(const float4*)(qrow + g * 4);
      qr[g * 4 + 0] = q4.x; qr[g * 4 + 1] = q4.y; qr[g * 4 + 2] = q4.z; qr[g * 4 + 3] = q4.w;
    }
    float sreg[44];
    float mx = -1e30f;
    int m0 = dh * 44;
    for (int mi = 0; mi < 44; mi++) {
      const float* krow = kl[m0 + mi];
      float s = 0.f;
#pragma unroll
      for (int d = 0; d < 32; d++) s += qr[d] * krow[d];
      s *= 0.17677669529663689f;
      sreg[mi] = s;
      mx = fmaxf(mx, s);
    }
    mx = fmaxf(mx, __shfl_xor(mx, 1, 64));
    float sum = 0.f;
    for (int mi = 0; mi < 44; mi++) { float e = __expf(sreg[mi] - mx); sreg[mi] = e; sum += e; }
    sum += __shfl_xor(sum, 1, 64);
    float inv = 1.f / sum;
    float o[32];
#pragma unroll
    for (int d = 0; d < 32; d++) o[d] = 0.f;
    for (int mi = 0; mi < 44; mi++) {
      float p = sreg[mi] * inv;
      const float* vrow = vl[m0 + mi];
#pragma unroll
      for (int d = 0; d < 32; d++) o[d] += p * vrow[d];
    }
#pragma unroll
    for (int d = 0; d < 32; d++) o[d] += __shfl_xor(o[d], 1, 64);
    unsigned short* orow = out + (size_t)(b * 88 + r) * 256 + h * 32 + dh * 16;
    uint4 u0, u1;
    int d0 = dh * 16;
    u0.x = pack2(o[d0 + 0], o[d0 + 1]);  u0.y = pack2(o[d0 + 2], o[d0 + 3]);
    u0.z = pack2(o[d0 + 4], o[d0 + 5]);  u0.w = pack2(o[d0 + 6], o[d0 + 7]);
    u1.x = pack2(o[d0 + 8], o[d0 + 9]);  u1.y = pack2(o[d0 + 10], o[d0 + 11]);
    u1.z = pack2(o[d0 + 12], o[d0 + 13]); u1.w = pack2(o[d0 + 14], o[d0 + 15]);
    *(uint4*)(orow) = u0;
    *(uint4*)(orow + 8) = u1;
  }
}

// ---------------------------------------------------------------------------
extern "C" void kernel_launch(void* const* d_in, const int* in_sizes, int n_in,
                              void* d_out, int out_size, void* d_ws, size_t ws_size,
                              hipStream_t stream) {
  (void)in_sizes; (void)n_in; (void)out_size; (void)ws_size;
  const float* pooled   = (const float*)d_in[0];
  const float* features = (const float*)d_in[1];
  const float* self_pe  = (const float*)d_in[2];
  const float* cross_pe = (const float*)d_in[3];
  const float* ln_qs_g = (const float*)d_in[4],  *ln_qs_b = (const float*)d_in[5];
  const float* ln_vs_g = (const float*)d_in[6],  *ln_vs_b = (const float*)d_in[7];
  const float* ln_qc_g = (const float*)d_in[8],  *ln_qc_b = (const float*)d_in[9];
  const float* ln_kv_g = (const float*)d_in[10], *ln_kv_b = (const float*)d_in[11];
  const float* ln_vc_g = (const float*)d_in[12], *ln_vc_b = (const float*)d_in[13];
  const float* ln_ffn_g = (const float*)d_in[14], *ln_ffn_b = (const float*)d_in[15];
  const float* Wq_s = (const float*)d_in[16], *Wk_s = (const float*)d_in[17];
  const float* Wv_s = (const float*)d_in[18], *Wp_s = (const float*)d_in[19];
  const float* Wq_c = (const float*)d_in[20], *Wk_c = (const float*)d_in[21];
  const float* Wv_c = (const float*)d_in[22], *Wp_c = (const float*)d_in[23];
  const float* bq_s = (const float*)d_in[24], *bv_s = (const float*)d_in[25];
  const float* bp_s = (const float*)d_in[26], *bq_c = (const float*)d_in[27];
  const float* bv_c = (const float*)d_in[28], *bp_c = (const float*)d_in[29];
  const float* W1 = (const float*)d_in[30], *b1 = (const float*)d_in[31];
  const float* W2 = (const float*)d_in[32], *b2 = (const float*)d_in[33];
  float* outp = (float*)d_out;
  char* ws = (char*)d_ws;

  // ---- workspace layout ----
  size_t off = 0;
  auto alloc = [&](size_t bytes) { size_t o = off; off = (off + bytes + 255) & ~(size_t)255; return o; };
  size_t QT   = alloc((size_t)BW_ * 2048 * 2);
  size_t CTX  = alloc((size_t)BW_ * 2048 * 2);
  size_t MQK  = alloc((size_t)2048 * 256 * 2);
  size_t MVP  = alloc((size_t)256 * 2048 * 2);
  size_t BQK  = alloc(2048 * 4);
  size_t BVP  = alloc(256 * 4);
  size_t WQKVS = alloc((size_t)768 * 256 * 2);
  size_t BQKVS = alloc(768 * 4);
  size_t WPS = alloc(65536 * 2);
  size_t W1T = alloc(262144 * 2), W2T = alloc(262144 * 2);
  size_t QN_C = alloc((size_t)BW_ * C_ * 2);
  size_t SPE  = alloc(64 * 4);
  size_t PART1 = alloc((size_t)48 * 16 * 88 * 256 * 4);   // 69.2 MB
  size_t PSTAT = alloc((size_t)48 * 16 * 3 * 2816 * 4);   // 26 MB
  size_t PRB   = alloc((size_t)BW_ * 256 * 4);            // 4.33 MB
  size_t S2A   = alloc((size_t)BW_ * 8 * 4);
  // phase-B overlays PART1 (dead after xattn_sm)
  size_t offp = PART1;
  auto allocP = [&](size_t bytes) { size_t o = offp; offp = (offp + bytes + 255) & ~(size_t)255; return o; };
  size_t X1    = allocP((size_t)BW_ * C_ * 4);
  size_t QN_S  = allocP((size_t)BW_ * C_ * 2);
  size_t VN_S  = allocP((size_t)BW_ * C_ * 2);
  size_t QKV_S = allocP((size_t)BW_ * 768 * 4);
  size_t S_O   = allocP((size_t)BW_ * C_ * 2);
  size_t X2    = allocP((size_t)BW_ * C_ * 4);
  size_t FFN   = allocP((size_t)BW_ * C_ * 2);
  size_t H1    = allocP((size_t)BW_ * F_ * 2);

  unsigned short* qtp  = (unsigned short*)(ws + QT);
  unsigned short* ctx  = (unsigned short*)(ws + CTX);
  unsigned short* mqk  = (unsigned short*)(ws + MQK);
  unsigned short* mvp  = (unsigned short*)(ws + MVP);
  float* bqk = (float*)(ws + BQK);
  float* bvp = (float*)(ws + BVP);
  unsigned short* wqkvs = (unsigned short*)(ws + WQKVS);
  float* bqkvs = (float*)(ws + BQKVS);
  unsigned short* wps = (unsigned short*)(ws + WPS);
  unsigned short* w1t = (unsigned short*)(ws + W1T), *w2t = (unsigned short*)(ws + W2T);
  unsigned short* qn_c = (unsigned short*)(ws + QN_C);
  float* spe   = (float*)(ws + SPE);
  float* part1 = (float*)(ws + PART1);
  float* pstat = (float*)(ws + PSTAT);
  float* prb   = (float*)(ws + PRB);
  float* s2a   = (float*)(ws + S2A);
  float*          x1   = (float*)(ws + X1);
  unsigned short* qn_s = (unsigned short*)(ws + QN_S);
  unsigned short* vn_s = (unsigned short*)(ws + VN_S);
  float* qkv_s = (float*)(ws + QKV_S);
  unsigned short* s_o  = (unsigned short*)(ws + S_O);
  float*          x2   = (float*)(ws + X2);
  unsigned short* ffn_n = (unsigned short*)(ws + FFN);
  unsigned short* h1    = (unsigned short*)(ws + H1);

  // 1. all prep in one launch
  prep_all<<<6018, 256, 0, stream>>>(
      Wq_s, Wk_s, Wv_s, Wp_s, W1, W2, Wq_c, Wk_c, Wv_c, Wp_c,
      bq_s, bv_s, bq_c, bv_c, bp_c, pooled, cross_pe, ln_qc_g, ln_qc_b,
      wqkvs, wps, w1t, w2t, mqk, mvp, bqk, bvp, bqkvs, spe, qn_c);

  // 2. q~ = qn_c @ Mqk^T + bqk  -> [BW,2048] bf16
  gemm_bt<<<(BW_ / 64) * (2048 / 64), 256, 0, stream>>>(qn_c, mqk, BW_, 2048, 256,
      bqk, nullptr, nullptr, qtp, 0);

  // 3-5. fused cross attention (no kn/vn materialization)
  xattn_score<<<768, 704, 0, stream>>>(features, qtp, ln_kv_g, cross_pe, part1, pstat);
  xattn_sm<<<BW_, 256, 0, stream>>>(part1, pstat, qtp, spe, ln_kv_g, ln_kv_b, prb, s2a);
  xattn_ctx<<<768, 704, 0, stream>>>(features, prb, s2a, ln_vc_g, ln_vc_b, ctx);

  // 6. x1 = ctx @ Mvp^T + bvp + pooled
  gemm_bt<<<(BW_ / 64) * (C_ / 64), 256, 0, stream>>>(ctx, mvp, BW_, C_, 2048,
      bvp, pooled, x1, nullptr, 0);

  // 7. qn_s = LN(x1+self_pe), vn_s = LN(x1)
  ln_dual<<<BW_, 256, 0, stream>>>(x1, self_pe, ln_qs_g, ln_qs_b,
                                   ln_vs_g, ln_vs_b, qn_s, vn_s);

  // 8. q|k from qn_s -> qkv_s cols [0,512); v from vn_s -> cols [512,768)
  gemm_bt_st<<<(BW_ / 64) * (512 / 64), 256, 0, stream>>>(qn_s, wqkvs, BW_, 512, 256,
      768, bqkvs, qkv_s);
  gemm_bt_st<<<(BW_ / 64) * (256 / 64), 256, 0, stream>>>(vn_s, wqkvs + 131072, BW_, 256, 256,
      768, bqkvs + 512, qkv_s + 512);

  // 9. self attention core
  self_attn3<<<B_ * 8, 192, 0, stream>>>(qkv_s, s_o);

  // 10. x2 = s_o @ Wp_s + bp_s + x1
  gemm_bt<<<(BW_ / 64) * (C_ / 64), 256, 0, stream>>>(s_o, wps, BW_, C_, C_,
      bp_s, x1, x2, nullptr, 0);

  // 11. FFN
  ln_rows<<<BW_, 256, 0, stream>>>(x2, ln_ffn_g, ln_ffn_b, ffn_n);
  gemm_bt<<<(BW_ / 64) * (F_ / 64), 256, 0, stream>>>(ffn_n, w1t, BW_, F_, C_,
      b1, nullptr, nullptr, h1, 1);
  gemm_bt<<<(BW_ / 64) * (C_ / 64), 256, 0, stream>>>(h1, w2t, BW_, C_, F_,
      b2, x2, outp, nullptr, 0);
}

// Round 7
// 581.063 us; speedup vs baseline: 1.5491x; 1.5491x over previous
//
#include <hip/hip_runtime.h>
#include <math.h>

// Problem dims
#define B_   48
#define W_   88
#define C_   256
#define H_   32
#define F_   1024
#define BW_  (B_ * W_)        // 4224
#define BWH_ (B_ * W_ * H_)   // 135168
#define HW_  (H_ * W_)        // 2816

typedef float  f32x4  __attribute__((ext_vector_type(4)));
typedef __bf16 bf16x8 __attribute__((ext_vector_type(8)));

__device__ __forceinline__ unsigned short f2bf(float f) {
  union { float f; unsigned int u; } v; v.f = f;
  unsigned int r = v.u + 0x7FFFu + ((v.u >> 16) & 1u);  // RNE
  return (unsigned short)(r >> 16);
}
__device__ __forceinline__ float bf2f(unsigned short h) {
  union { unsigned int u; float f; } v; v.u = ((unsigned int)h) << 16;
  return v.f;
}
__device__ __forceinline__ unsigned int pack2(float a, float b) {
  return (unsigned int)f2bf(a) | ((unsigned int)f2bf(b) << 16);
}

// ---------------------------------------------------------------------------
// prep_all: every weight-prep step in ONE launch.
// ---------------------------------------------------------------------------
__global__ __launch_bounds__(256) void prep_all(
    const float* __restrict__ Wq_s, const float* __restrict__ Wk_s,
    const float* __restrict__ Wv_s, const float* __restrict__ Wp_s,
    const float* __restrict__ W1, const float* __restrict__ W2,
    const float* __restrict__ Wq_c, const float* __restrict__ Wk_c,
    const float* __restrict__ Wv_c, const float* __restrict__ Wp_c,
    const float* __restrict__ bq_s, const float* __restrict__ bv_s,
    const float* __restrict__ bq_c, const float* __restrict__ bv_c,
    const float* __restrict__ bp_c,
    const float* __restrict__ pooled, const float* __restrict__ cross_pe,
    const float* __restrict__ ln_qc_g, const float* __restrict__ ln_qc_b,
    unsigned short* __restrict__ wqkvs, unsigned short* __restrict__ wps,
    unsigned short* __restrict__ w1t, unsigned short* __restrict__ w2t,
    unsigned short* __restrict__ mqk, unsigned short* __restrict__ mvp,
    float* __restrict__ bqk, float* __restrict__ bvp,
    float* __restrict__ bqkvs, float* __restrict__ spe,
    unsigned short* __restrict__ qn_c) {
  __shared__ float smem[256 * 33 + 4 * 33];
  int blk = blockIdx.x, t = threadIdx.x;

  if (blk < 768) {
    const float* src; unsigned short* dst; int Cc, R, tile;
    if (blk < 64)       { src = Wq_s; dst = wqkvs;          Cc = 256;  R = 256;  tile = blk; }
    else if (blk < 128) { src = Wk_s; dst = wqkvs + 65536;  Cc = 256;  R = 256;  tile = blk - 64; }
    else if (blk < 192) { src = Wv_s; dst = wqkvs + 131072; Cc = 256;  R = 256;  tile = blk - 128; }
    else if (blk < 256) { src = Wp_s; dst = wps;            Cc = 256;  R = 256;  tile = blk - 192; }
    else if (blk < 512) { src = W1;   dst = w1t;            Cc = 1024; R = 256;  tile = blk - 256; }
    else                { src = W2;   dst = w2t;            Cc = 256;  R = 1024; tile = blk - 512; }
    int tcn = Cc >> 5;
    int tr = tile / tcn, tc = tile % tcn;
    float (*lds)[33] = (float(*)[33])smem;
    int r = t >> 3, c4 = (t & 7) * 4;
    float4 v = *(const float4*)(src + (size_t)(tr * 32 + r) * Cc + tc * 32 + c4);
    lds[r][c4 + 0] = v.x; lds[r][c4 + 1] = v.y; lds[r][c4 + 2] = v.z; lds[r][c4 + 3] = v.w;
    __syncthreads();
    int rd = t >> 3, cd4 = (t & 7) * 4;
    uint2 u;
    u.x = pack2(lds[cd4 + 0][rd], lds[cd4 + 1][rd]);
    u.y = pack2(lds[cd4 + 2][rd], lds[cd4 + 3][rd]);
    *(uint2*)(dst + (size_t)(tc * 32 + rd) * R + tr * 32 + cd4) = u;
  } else if (blk < 1280) {
    int lb = blk - 768;
    int h = lb >> 6, cb = lb & 63;
    float (*wq)[33] = (float(*)[33])smem;
    float (*wk)[33] = (float(*)[33])(smem + 256 * 33);
#pragma unroll
    for (int p = 0; p < 8; p++) {
      int dp = (t >> 3) + 32 * p, d4 = (t & 7) * 4;
      float4 v = *(const float4*)(Wq_c + (size_t)dp * 256 + 32 * h + d4);
      wq[dp][d4 + 0] = v.x; wq[dp][d4 + 1] = v.y; wq[dp][d4 + 2] = v.z; wq[dp][d4 + 3] = v.w;
    }
    if (t < 128) {
      int c_l = t >> 5, dd = t & 31;
      wk[c_l][dd] = Wk_c[(size_t)(cb * 4 + c_l) * 256 + 32 * h + dd];
    }
    __syncthreads();
    const float scale = 0.17677669529663689f;
    int c_l = t >> 6, ln = t & 63;
    int n = 256 * h + cb * 4 + c_l;
#pragma unroll
    for (int j = 0; j < 4; j++) {
      int dp = ln + 64 * j;
      float acc = 0.f;
#pragma unroll
      for (int dd = 0; dd < 32; dd++) acc += wq[dp][dd] * wk[c_l][dd];
      mqk[(size_t)n * 256 + dp] = f2bf(acc * scale);
    }
    if (ln == 0) {
      float bb = 0.f;
#pragma unroll
      for (int dd = 0; dd < 32; dd++) bb += bq_c[32 * h + dd] * wk[c_l][dd];
      bqk[n] = bb * scale;
    }
  } else if (blk < 1792) {
    int lb = blk - 1280;
    int h = lb >> 6, db = lb & 63;
    float (*wv)[33] = (float(*)[33])smem;
    float (*wp)[33] = (float(*)[33])(smem + 256 * 33);
#pragma unroll
    for (int p = 0; p < 8; p++) {
      int c = (t >> 3) + 32 * p, d4 = (t & 7) * 4;
      float4 v = *(const float4*)(Wv_c + (size_t)c * 256 + 32 * h + d4);
      wv[c][d4 + 0] = v.x; wv[c][d4 + 1] = v.y; wv[c][d4 + 2] = v.z; wv[c][d4 + 3] = v.w;
    }
    if (t < 128) {
      int d_l = t >> 5, dd = t & 31;
      wp[d_l][dd] = Wp_c[(size_t)(32 * h + dd) * 256 + db * 4 + d_l];
    }
    __syncthreads();
    int d_l = t >> 6, ln = t & 63;
    int d = db * 4 + d_l;
#pragma unroll
    for (int j = 0; j < 4; j++) {
      int c = ln + 64 * j;
      float acc = 0.f;
#pragma unroll
      for (int dd = 0; dd < 32; dd++) acc += wv[c][dd] * wp[d_l][dd];
      mvp[(size_t)d * 2048 + 256 * h + c] = f2bf(acc);
    }
  } else if (blk == 1792) {
    float acc = bp_c[t];
    for (int dp = 0; dp < 256; dp++) acc += bv_c[dp] * Wp_c[(size_t)dp * 256 + t];
    bvp[t] = acc;
    bqkvs[t] = bq_s[t]; bqkvs[256 + t] = 0.f; bqkvs[512 + t] = bv_s[t];
  } else if (blk == 1793) {
    int j = t >> 3, cp = t & 7;
    float sp = 0.f, sp2 = 0.f;
    for (int i = 0; i < 32; i++) {
      float v = cross_pe[j * 256 + cp * 32 + i];
      sp += v; sp2 += v * v;
    }
    smem[j * 8 + cp] = sp; smem[256 + j * 8 + cp] = sp2;
    __syncthreads();
    if (t < 32) {
      float a = 0.f, a2 = 0.f;
      for (int i = 0; i < 8; i++) { a += smem[t * 8 + i]; a2 += smem[256 + t * 8 + i]; }
      spe[t] = a; spe[32 + t] = a2;
    }
  } else {
    int row = blk - 1794, c = t;
    float v = pooled[(size_t)row * C_ + c];
    float s1 = v, s2 = v * v;
#pragma unroll
    for (int m = 32; m > 0; m >>= 1) {
      s1 += __shfl_xor(s1, m, 64); s2 += __shfl_xor(s2, m, 64);
    }
    float* red = smem;
    int wave = c >> 6;
    if ((c & 63) == 0) { red[wave] = s1; red[4 + wave] = s2; }
    __syncthreads();
    s1 = red[0] + red[1] + red[2] + red[3];
    s2 = red[4] + red[5] + red[6] + red[7];
    float mu = s1 * (1.f / C_);
    float rs = rsqrtf(s2 * (1.f / C_) - mu * mu + 1e-5f);
    qn_c[(size_t)row * C_ + c] = f2bf((v - mu) * rs * ln_qc_g[c] + ln_qc_b[c]);
  }
}

// ---------------------------------------------------------------------------
// xattn_score (K1): block=(b, c-chunk of 16), 704 threads (w,head).
// Per-quarter register accumulators (NO dynamically-indexed private arrays —
// R6's a1[32] spilled to scratch: 374MB WRITE_SIZE). part1 bf16 [q][head][i].
// ---------------------------------------------------------------------------
__global__ __launch_bounds__(704) void xattn_score(
    const float* __restrict__ features, const unsigned short* __restrict__ qt,
    const float* __restrict__ gk, const float* __restrict__ cross_pe,
    unsigned short* __restrict__ part1, float* __restrict__ pstat) {
  int b = blockIdx.x >> 4, ch = blockIdx.x & 15, c0 = ch * 16;
  __shared__ unsigned short kvl[2][16 * 8 * 88];
  __shared__ float pel[32][16];
  int t = threadIdx.x, w = t >> 3, head = t & 7;
  if (t < 512) {
    int j = t >> 4, c = t & 15;
    pel[j][c] = cross_pe[j * 256 + c0 + c];
  }
  float gq[16];
  {
    const unsigned short* qrow = qt + (size_t)(b * 88 + w) * 2048 + head * 256 + c0;
    bf16x8 q0 = *(const bf16x8*)qrow;
    bf16x8 q1 = *(const bf16x8*)(qrow + 8);
#pragma unroll
    for (int i = 0; i < 8; i++) {
      gq[i]     = gk[c0 + i]     * (float)q0[i];
      gq[8 + i] = gk[c0 + 8 + i] * (float)q1[i];
    }
  }
  const float* fbase = features + (size_t)(b * 256 + c0) * HW_;
  float4 rg[4];
  int iA[4];
  auto loadq = [&](int q) {
#pragma unroll
    for (int k = 0; k < 4; k++) {
      int p4 = t + k * 704;
      int c = p4 / 176, r = p4 - c * 176;
      int j8 = r / 22, w4 = (r - j8 * 22) * 4;
      iA[k] = c * 704 + j8 * 88 + w4;
      rg[k] = *(const float4*)(fbase + (size_t)c * HW_ + (q * 8 + j8) * 88 + w4);
    }
  };
  auto storeq = [&](int buf) {
#pragma unroll
    for (int k = 0; k < 4; k++) {
      uint2 u;
      u.x = pack2(rg[k].x, rg[k].y);
      u.y = pack2(rg[k].z, rg[k].w);
      *(uint2*)&kvl[buf][iA[k]] = u;
    }
  };
  unsigned short* dst = part1 + (size_t)((b * 16 + ch) * 88 + w) * 256;
  loadq(0); storeq(0);
  __syncthreads();
  for (int q = 0; q < 4; q++) {
    int cur = q & 1;
    if (q < 3) loadq(q + 1);
    const unsigned short* kb = kvl[cur];
    float a1q[8];
#pragma unroll
    for (int i = 0; i < 8; i++) a1q[i] = 0.f;
#pragma unroll
    for (int c = 0; c < 16; c++) {
      float g = gq[c];
      const unsigned short* row = kb + c * 704 + w;
#pragma unroll
      for (int j8 = 0; j8 < 8; j8++)
        a1q[j8] += g * (bf2f(row[j8 * 88]) + pel[q * 8 + j8][c]);
    }
    {
      float s1 = 0.f, s2 = 0.f, cr = 0.f;
#pragma unroll
      for (int c = 0; c < 16; c++) {
        float v = bf2f(kb[c * 704 + head * 88 + w]);
        s1 += v; s2 += v * v; cr += v * pel[q * 8 + head][c];
      }
      size_t sb = (size_t)(b * 16 + ch) * 3 * 2816 + (q * 8 + head) * 88 + w;
      pstat[sb] = s1; pstat[sb + 2816] = s2; pstat[sb + 5632] = cr;
    }
    {
      unsigned short pk[8];
#pragma unroll
      for (int i = 0; i < 8; i++) pk[i] = f2bf(a1q[i]);
      *(uint4*)(dst + q * 64 + head * 8) = *(uint4*)pk;
    }
    if (q < 3) storeq(cur ^ 1);
    __syncthreads();
  }
}

// ---------------------------------------------------------------------------
// xattn_sm (K2): block per (b,w). Reduce partials, LN algebra, softmax.
// part1 row layout: [q(4)][head(8)][i(8)] bf16.
// ---------------------------------------------------------------------------
__global__ __launch_bounds__(256) void xattn_sm(
    const unsigned short* __restrict__ part1, const float* __restrict__ pstat,
    const unsigned short* __restrict__ qt, const float* __restrict__ spe,
    const float* __restrict__ gk, const float* __restrict__ bk,
    float* __restrict__ pr, float* __restrict__ s2a) {
  int bw = blockIdx.x, b = bw / 88, w = bw - b * 88;
  int t = threadIdx.x, head = t >> 5, j = t & 31;
  __shared__ float statl[3][32];
  int pidx = ((j >> 3) << 6) + head * 8 + (j & 7);
  float a1 = 0.f;
  for (int ch = 0; ch < 16; ch++)
    a1 += bf2f(part1[(size_t)((b * 16 + ch) * 88 + w) * 256 + pidx]);
  if (t < 96) {
    int s = t >> 5, jj = t & 31;
    float v = 0.f;
    for (int ch = 0; ch < 16; ch++)
      v += pstat[(size_t)(b * 16 + ch) * 3 * 2816 + s * 2816 + jj * 88 + w];
    statl[s][jj] = v;
  }
  __syncthreads();
  float s1 = statl[0][j], s2v = statl[1][j], cr = statl[2][j];
  float mu  = s1 * (1.f / 256.f);
  float rs  = rsqrtf(s2v * (1.f / 256.f) - mu * mu + 1e-5f);
  float muk = (s1 + spe[j]) * (1.f / 256.f);
  float rsk = rsqrtf((s2v + 2.f * cr + spe[32 + j]) * (1.f / 256.f) - muk * muk + 1e-5f);
  float a3 = 0.f, a4 = 0.f;
  {
    const unsigned short* qrow = qt + (size_t)bw * 2048 + head * 256 + j * 8;
#pragma unroll
    for (int i = 0; i < 8; i++) {
      int c = j * 8 + i;
      float qv = bf2f(qrow[i]);
      a3 += bk[c] * qv; a4 += gk[c] * qv;
    }
  }
#pragma unroll
  for (int m = 16; m > 0; m >>= 1) { a3 += __shfl_xor(a3, m, 32); a4 += __shfl_xor(a4, m, 32); }
  float s = rsk * a1 + a3 - muk * rsk * a4;
  float mx = s;
#pragma unroll
  for (int m = 16; m > 0; m >>= 1) mx = fmaxf(mx, __shfl_xor(mx, m, 32));
  float e = __expf(s - mx);
  float sum = e;
#pragma unroll
  for (int m = 16; m > 0; m >>= 1) sum += __shfl_xor(sum, m, 32);
  float p = e / sum;
  pr[((size_t)bw * 8 + head) * 32 + j] = p * rs;
  float sp = p * rs * mu;
#pragma unroll
  for (int m = 16; m > 0; m >>= 1) sp += __shfl_xor(sp, m, 32);
  if (j == 0) s2a[(size_t)bw * 8 + head] = sp;
}

// ---------------------------------------------------------------------------
// xattn_ctx (K3): second features pass weighted by pr (loaded per quarter —
// no dynamically-indexed private arrays). ctx bf16 [bw][head*256+c].
// ---------------------------------------------------------------------------
__global__ __launch_bounds__(704) void xattn_ctx(
    const float* __restrict__ features, const float* __restrict__ pr,
    const float* __restrict__ s2a, const float* __restrict__ gv,
    const float* __restrict__ bvv, unsigned short* __restrict__ ctx) {
  int b = blockIdx.x >> 4, ch = blockIdx.x & 15, c0 = ch * 16;
  __shared__ unsigned short kvl[2][16 * 8 * 88];
  int t = threadIdx.x, w = t >> 3, head = t & 7;
  float S2 = s2a[(size_t)(b * 88 + w) * 8 + head];
  float U[16];
#pragma unroll
  for (int i = 0; i < 16; i++) U[i] = 0.f;

  const float* fbase = features + (size_t)(b * 256 + c0) * HW_;
  const float* prbase = pr + ((size_t)(b * 88 + w) * 8 + head) * 32;
  float4 rg[4];
  int iA[4];
  auto loadq = [&](int q) {
#pragma unroll
    for (int k = 0; k < 4; k++) {
      int p4 = t + k * 704;
      int c = p4 / 176, r = p4 - c * 176;
      int j8 = r / 22, w4 = (r - j8 * 22) * 4;
      iA[k] = c * 704 + j8 * 88 + w4;
      rg[k] = *(const float4*)(fbase + (size_t)c * HW_ + (q * 8 + j8) * 88 + w4);
    }
  };
  auto storeq = [&](int buf) {
#pragma unroll
    for (int k = 0; k < 4; k++) {
      uint2 u;
      u.x = pack2(rg[k].x, rg[k].y);
      u.y = pack2(rg[k].z, rg[k].w);
      *(uint2*)&kvl[buf][iA[k]] = u;
    }
  };
  loadq(0); storeq(0);
  __syncthreads();
  for (int q = 0; q < 4; q++) {
    int cur = q & 1;
    if (q < 3) loadq(q + 1);
    const unsigned short* kb = kvl[cur];
    float4 p0 = *(const float4*)(prbase + q * 8);
    float4 p1 = *(const float4*)(prbase + q * 8 + 4);
    float prr8[8] = {p0.x, p0.y, p0.z, p0.w, p1.x, p1.y, p1.z, p1.w};
#pragma unroll
    for (int c = 0; c < 16; c++) {
      const unsigned short* row = kb + c * 704 + w;
      float acc = U[c];
#pragma unroll
      for (int j8 = 0; j8 < 8; j8++)
        acc += prr8[j8] * bf2f(row[j8 * 88]);
      U[c] = acc;
    }
    if (q < 3) storeq(cur ^ 1);
    __syncthreads();
  }
  unsigned short* orow = ctx + (size_t)(b * 88 + w) * 2048 + head * 256 + c0;
  unsigned short pk[16];
#pragma unroll
  for (int i = 0; i < 16; i++)
    pk[i] = f2bf(gv[c0 + i] * (U[i] - S2) + bvv[c0 + i]);
  *(uint4*)(orow) = *(uint4*)pk;
  *(uint4*)(orow + 8) = *(uint4*)(pk + 8);
}

// ---------------------------------------------------------------------------
// Row LayerNorm: x f32 [rows, C_] -> bf16 out
// ---------------------------------------------------------------------------
__global__ __launch_bounds__(256) void ln_rows(
    const float* __restrict__ x,
    const float* __restrict__ g, const float* __restrict__ bta,
    unsigned short* __restrict__ out) {
  int row = blockIdx.x, c = threadIdx.x;
  float v = x[(size_t)row * C_ + c];
  float s1 = v, s2 = v * v;
#pragma unroll
  for (int m = 32; m > 0; m >>= 1) {
    s1 += __shfl_xor(s1, m, 64);
    s2 += __shfl_xor(s2, m, 64);
  }
  __shared__ float red[8];
  int wave = c >> 6;
  if ((c & 63) == 0) { red[wave] = s1; red[4 + wave] = s2; }
  __syncthreads();
  s1 = red[0] + red[1] + red[2] + red[3];
  s2 = red[4] + red[5] + red[6] + red[7];
  float mu = s1 * (1.f / C_);
  float rs = rsqrtf(s2 * (1.f / C_) - mu * mu + 1e-5f);
  out[(size_t)row * C_ + c] = f2bf((v - mu) * rs * g[c] + bta[c]);
}

// ---------------------------------------------------------------------------
// ln_dual: out1 = LN(x+pe)*g1+b1, out2 = LN(x)*g2+b2. One read of x.
// ---------------------------------------------------------------------------
__global__ __launch_bounds__(256) void ln_dual(
    const float* __restrict__ x, const float* __restrict__ pe,
    const float* __restrict__ g1, const float* __restrict__ b1a,
    const float* __restrict__ g2, const float* __restrict__ b2a,
    unsigned short* __restrict__ out1, unsigned short* __restrict__ out2) {
  int row = blockIdx.x, c = threadIdx.x;
  float v = x[(size_t)row * C_ + c];
  float vp = v + pe[(size_t)(row % 88) * C_ + c];
  float s1 = v, s2 = v * v, t1 = vp, t2 = vp * vp;
#pragma unroll
  for (int m = 32; m > 0; m >>= 1) {
    s1 += __shfl_xor(s1, m, 64); s2 += __shfl_xor(s2, m, 64);
    t1 += __shfl_xor(t1, m, 64); t2 += __shfl_xor(t2, m, 64);
  }
  __shared__ float red[16];
  int wave = c >> 6;
  if ((c & 63) == 0) {
    red[wave] = s1; red[4 + wave] = s2; red[8 + wave] = t1; red[12 + wave] = t2;
  }
  __syncthreads();
  s1 = red[0] + red[1] + red[2] + red[3];
  s2 = red[4] + red[5] + red[6] + red[7];
  t1 = red[8] + red[9] + red[10] + red[11];
  t2 = red[12] + red[13] + red[14] + red[15];
  float mu = s1 * (1.f / C_), rs = rsqrtf(s2 * (1.f / C_) - mu * mu + 1e-5f);
  float mup = t1 * (1.f / C_), rsp = rsqrtf(t2 * (1.f / C_) - mup * mup + 1e-5f);
  out1[(size_t)row * C_ + c] = f2bf((vp - mup) * rsp * g1[c] + b1a[c]);
  out2[(size_t)row * C_ + c] = f2bf((v - mu) * rs * g2[c] + b2a[c]);
}

// ---------------------------------------------------------------------------
// GEMM: out[M,N] = A[M,K](bf16) @ Bt[N,K](bf16)^T, fp32 acc, reg double-buffer.
// ---------------------------------------------------------------------------
__global__ __launch_bounds__(256) void gemm_bt(
    const unsigned short* __restrict__ A, const unsigned short* __restrict__ Bt,
    int M, int N, int K,
    const float* __restrict__ bias, const float* __restrict__ resid,
    float* __restrict__ outF, unsigned short* __restrict__ outB, int act_gelu) {
  __shared__ __attribute__((aligned(16))) unsigned short As[64][32];
  __shared__ __attribute__((aligned(16))) unsigned short Bs[64][32];
  const int tiles_n = N >> 6;
  const int bm = blockIdx.x / tiles_n;
  const int bn = blockIdx.x % tiles_n;
  const int tid = threadIdx.x;
  const int wave = tid >> 6, lane = tid & 63;
  const int quad = lane >> 4, lr = lane & 15;
  const int wm = (wave >> 1) << 5, wn = (wave & 1) << 5;
  const int lrow = tid >> 2;
  const int lcol = (tid & 3) << 3;
  const size_t a_base = (size_t)(bm * 64 + lrow) * K + lcol;
  const size_t b_base = (size_t)(bn * 64 + lrow) * K + lcol;
  f32x4 acc[2][2] = {};
  uint4 areg = *(const uint4*)(A + a_base);
  uint4 breg = *(const uint4*)(Bt + b_base);
  for (int k0 = 0; k0 < K; k0 += 32) {
    *(uint4*)&As[lrow][lcol] = areg;
    *(uint4*)&Bs[lrow][lcol] = breg;
    __syncthreads();
    if (k0 + 32 < K) {
      areg = *(const uint4*)(A + a_base + k0 + 32);
      breg = *(const uint4*)(Bt + b_base + k0 + 32);
    }
    bf16x8 af0 = *(const bf16x8*)&As[wm + lr][quad << 3];
    bf16x8 af1 = *(const bf16x8*)&As[wm + 16 + lr][quad << 3];
    bf16x8 bf0 = *(const bf16x8*)&Bs[wn + lr][quad << 3];
    bf16x8 bf1 = *(const bf16x8*)&Bs[wn + 16 + lr][quad << 3];
    acc[0][0] = __builtin_amdgcn_mfma_f32_16x16x32_bf16(af0, bf0, acc[0][0], 0, 0, 0);
    acc[0][1] = __builtin_amdgcn_mfma_f32_16x16x32_bf16(af0, bf1, acc[0][1], 0, 0, 0);
    acc[1][0] = __builtin_amdgcn_mfma_f32_16x16x32_bf16(af1, bf0, acc[1][0], 0, 0, 0);
    acc[1][1] = __builtin_amdgcn_mfma_f32_16x16x32_bf16(af1, bf1, acc[1][1], 0, 0, 0);
    __syncthreads();
  }
#pragma unroll
  for (int i = 0; i < 2; i++)
#pragma unroll
    for (int j = 0; j < 2; j++)
#pragma unroll
      for (int rr = 0; rr < 4; rr++) {
        int row = bm * 64 + wm + i * 16 + quad * 4 + rr;
        int col = bn * 64 + wn + j * 16 + lr;
        float val = acc[i][j][rr];
        if (bias) val += bias[col];
        if (act_gelu) val = 0.5f * val * (1.f + erff(val * 0.70710678118654752f));
        if (resid) val += resid[(size_t)row * N + col];
        if (outF) outF[(size_t)row * N + col] = val;
        else outB[(size_t)row * N + col] = f2bf(val);
      }
}

// ---------------------------------------------------------------------------
// gemm_bt_st: like gemm_bt but writes f32 with row stride ldc (+bias).
// ---------------------------------------------------------------------------
__global__ __launch_bounds__(256) void gemm_bt_st(
    const unsigned short* __restrict__ A, const unsigned short* __restrict__ Bt,
    int M, int N, int K, int ldc,
    const float* __restrict__ bias, float* __restrict__ outF) {
  __shared__ __attribute__((aligned(16))) unsigned short As[64][32];
  __shared__ __attribute__((aligned(16))) unsigned short Bs[64][32];
  const int tiles_n = N >> 6;
  const int bm = blockIdx.x / tiles_n;
  const int bn = blockIdx.x % tiles_n;
  const int tid = threadIdx.x;
  const int wave = tid >> 6, lane = tid & 63;
  const int quad = lane >> 4, lr = lane & 15;
  const int wm = (wave >> 1) << 5, wn = (wave & 1) << 5;
  const int lrow = tid >> 2;
  const int lcol = (tid & 3) << 3;
  const size_t a_base = (size_t)(bm * 64 + lrow) * K + lcol;
  const size_t b_base = (size_t)(bn * 64 + lrow) * K + lcol;
  f32x4 acc[2][2] = {};
  uint4 areg = *(const uint4*)(A + a_base);
  uint4 breg = *(const uint4*)(Bt + b_base);
  for (int k0 = 0; k0 < K; k0 += 32) {
    *(uint4*)&As[lrow][lcol] = areg;
    *(uint4*)&Bs[lrow][lcol] = breg;
    __syncthreads();
    if (k0 + 32 < K) {
      areg = *(const uint4*)(A + a_base + k0 + 32);
      breg = *(const uint4*)(Bt + b_base + k0 + 32);
    }
    bf16x8 af0 = *(const bf16x8*)&As[wm + lr][quad << 3];
    bf16x8 af1 = *(const bf16x8*)&As[wm + 16 + lr][quad << 3];
    bf16x8 bf0 = *(const bf16x8*)&Bs[wn + lr][quad << 3];
    bf16x8 bf1 = *(const bf16x8*)&Bs[wn + 16 + lr][quad << 3];
    acc[0][0] = __builtin_amdgcn_mfma_f32_16x16x32_bf16(af0, bf0, acc[0][0], 0, 0, 0);
    acc[0][1] = __builtin_amdgcn_mfma_f32_16x16x32_bf16(af0, bf1, acc[0][1], 0, 0, 0);
    acc[1][0] = __builtin_amdgcn_mfma_f32_16x16x32_bf16(af1, bf0, acc[1][0], 0, 0, 0);
    acc[1][1] = __builtin_amdgcn_mfma_f32_16x16x32_bf16(af1, bf1, acc[1][1], 0, 0, 0);
    __syncthreads();
  }
#pragma unroll
  for (int i = 0; i < 2; i++)
#pragma unroll
    for (int j = 0; j < 2; j++)
#pragma unroll
      for (int rr = 0; rr < 4; rr++) {
        int row = bm * 64 + wm + i * 16 + quad * 4 + rr;
        int col = bn * 64 + wn + j * 16 + lr;
        outF[(size_t)row * ldc + col] = acc[i][j][rr] + bias[col];
      }
}

// ---------------------------------------------------------------------------
// self_attn3: block=(b,h), 192 threads: pair (r=t>>1, dh=t&1) per query row.
// ---------------------------------------------------------------------------
__global__ __launch_bounds__(192) void self_attn3(
    const float* __restrict__ qkv, unsigned short* __restrict__ out) {
  int b = blockIdx.x >> 3;
  int h = blockIdx.x & 7;
  int t = threadIdx.x;
  __shared__ float kl[88][33];
  __shared__ float vl[88][33];
  for (int i = t; i < 704; i += 192) {
    int m = i >> 3, d4 = (i & 7) << 2;
    float4 kv4 = *(const float4*)(qkv + (size_t)(b * 88 + m) * 768 + 256 + h * 32 + d4);
    float4 vv4 = *(const float4*)(qkv + (size_t)(b * 88 + m) * 768 + 512 + h * 32 + d4);
    kl[m][d4 + 0] = kv4.x; kl[m][d4 + 1] = kv4.y; kl[m][d4 + 2] = kv4.z; kl[m][d4 + 3] = kv4.w;
    vl[m][d4 + 0] = vv4.x; vl[m][d4 + 1] = vv4.y; vl[m][d4 + 2] = vv4.z; vl[m][d4 + 3] = vv4.w;
  }
  __syncthreads();
  int r = t >> 1, dh = t & 1;
  if (r < 88) {
    const float* qrow = qkv + (size_t)(b * 88 + r) * 768 + h * 32;
    float qr[32];
#pragma unroll
    for (int g = 0; g < 8; g++) {
      float4 q4 = *(const float4*)(qrow + g * 4);
      qr[g * 4 + 0] = q4.x; qr[g * 4 + 1] = q4.y; qr[g * 4 + 2] = q4.z; qr[g * 4 + 3] = q4.w;
    }
    float sreg[44];
    float mx = -1e30f;
    int m0 = dh * 44;
    for (int mi = 0; mi < 44; mi++) {
      const float* krow = kl[m0 + mi];
      float s = 0.f;
#pragma unroll
      for (int d = 0; d < 32; d++) s += qr[d] * krow[d];
      s *= 0.17677669529663689f;
      sreg[mi] = s;
      mx = fmaxf(mx, s);
    }
    mx = fmaxf(mx, __shfl_xor(mx, 1, 64));
    float sum = 0.f;
    for (int mi = 0; mi < 44; mi++) { float e = __expf(sreg[mi] - mx); sreg[mi] = e; sum += e; }
    sum += __shfl_xor(sum, 1, 64);
    float inv = 1.f / sum;
    float o[32];
#pragma unroll
    for (int d = 0; d < 32; d++) o[d] = 0.f;
    for (int mi = 0; mi < 44; mi++) {
      float p = sreg[mi] * inv;
      const float* vrow = vl[m0 + mi];
#pragma unroll
      for (int d = 0; d < 32; d++) o[d] += p * vrow[d];
    }
#pragma unroll
    for (int d = 0; d < 32; d++) o[d] += __shfl_xor(o[d], 1, 64);
    unsigned short* orow = out + (size_t)(b * 88 + r) * 256 + h * 32 + dh * 16;
    uint4 u0, u1;
    int d0 = dh * 16;
    u0.x = pack2(o[d0 + 0], o[d0 + 1]);  u0.y = pack2(o[d0 + 2], o[d0 + 3]);
    u0.z = pack2(o[d0 + 4], o[d0 + 5]);  u0.w = pack2(o[d0 + 6], o[d0 + 7]);
    u1.x = pack2(o[d0 + 8], o[d0 + 9]);  u1.y = pack2(o[d0 + 10], o[d0 + 11]);
    u1.z = pack2(o[d0 + 12], o[d0 + 13]); u1.w = pack2(o[d0 + 14], o[d0 + 15]);
    *(uint4*)(orow) = u0;
    *(uint4*)(orow + 8) = u1;
  }
}

// ---------------------------------------------------------------------------
extern "C" void kernel_launch(void* const* d_in, const int* in_sizes, int n_in,
                              void* d_out, int out_size, void* d_ws, size_t ws_size,
                              hipStream_t stream) {
  (void)in_sizes; (void)n_in; (void)out_size; (void)ws_size;
  const float* pooled   = (const float*)d_in[0];
  const float* features = (const float*)d_in[1];
  const float* self_pe  = (const float*)d_in[2];
  const float* cross_pe = (const float*)d_in[3];
  const float* ln_qs_g = (const float*)d_in[4],  *ln_qs_b = (const float*)d_in[5];
  const float* ln_vs_g = (const float*)d_in[6],  *ln_vs_b = (const float*)d_in[7];
  const float* ln_qc_g = (const float*)d_in[8],  *ln_qc_b = (const float*)d_in[9];
  const float* ln_kv_g = (const float*)d_in[10], *ln_kv_b = (const float*)d_in[11];
  const float* ln_vc_g = (const float*)d_in[12], *ln_vc_b = (const float*)d_in[13];
  const float* ln_ffn_g = (const float*)d_in[14], *ln_ffn_b = (const float*)d_in[15];
  const float* Wq_s = (const float*)d_in[16], *Wk_s = (const float*)d_in[17];
  const float* Wv_s = (const float*)d_in[18], *Wp_s = (const float*)d_in[19];
  const float* Wq_c = (const float*)d_in[20], *Wk_c = (const float*)d_in[21];
  const float* Wv_c = (const float*)d_in[22], *Wp_c = (const float*)d_in[23];
  const float* bq_s = (const float*)d_in[24], *bv_s = (const float*)d_in[25];
  const float* bp_s = (const float*)d_in[26], *bq_c = (const float*)d_in[27];
  const float* bv_c = (const float*)d_in[28], *bp_c = (const float*)d_in[29];
  const float* W1 = (const float*)d_in[30], *b1 = (const float*)d_in[31];
  const float* W2 = (const float*)d_in[32], *b2 = (const float*)d_in[33];
  float* outp = (float*)d_out;
  char* ws = (char*)d_ws;

  // ---- workspace layout ----
  size_t off = 0;
  auto alloc = [&](size_t bytes) { size_t o = off; off = (off + bytes + 255) & ~(size_t)255; return o; };
  size_t QT   = alloc((size_t)BW_ * 2048 * 2);
  size_t CTX  = alloc((size_t)BW_ * 2048 * 2);
  size_t MQK  = alloc((size_t)2048 * 256 * 2);
  size_t MVP  = alloc((size_t)256 * 2048 * 2);
  size_t BQK  = alloc(2048 * 4);
  size_t BVP  = alloc(256 * 4);
  size_t WQKVS = alloc((size_t)768 * 256 * 2);
  size_t BQKVS = alloc(768 * 4);
  size_t WPS = alloc(65536 * 2);
  size_t W1T = alloc(262144 * 2), W2T = alloc(262144 * 2);
  size_t QN_C = alloc((size_t)BW_ * C_ * 2);
  size_t SPE  = alloc(64 * 4);
  size_t PART1 = alloc((size_t)48 * 16 * 88 * 256 * 2);   // 34.6 MB bf16
  size_t PSTAT = alloc((size_t)48 * 16 * 3 * 2816 * 4);   // 26 MB
  size_t PRB   = alloc((size_t)BW_ * 256 * 4);
  size_t S2A   = alloc((size_t)BW_ * 8 * 4);
  // phase-B overlays PART1+PSTAT (both dead after xattn_sm; 60.6MB > 39MB needed)
  size_t offp = PART1;
  auto allocP = [&](size_t bytes) { size_t o = offp; offp = (offp + bytes + 255) & ~(size_t)255; return o; };
  size_t X1    = allocP((size_t)BW_ * C_ * 4);
  size_t QN_S  = allocP((size_t)BW_ * C_ * 2);
  size_t VN_S  = allocP((size_t)BW_ * C_ * 2);
  size_t QKV_S = allocP((size_t)BW_ * 768 * 4);
  size_t S_O   = allocP((size_t)BW_ * C_ * 2);
  size_t X2    = allocP((size_t)BW_ * C_ * 4);
  size_t FFN   = allocP((size_t)BW_ * C_ * 2);
  size_t H1    = allocP((size_t)BW_ * F_ * 2);

  unsigned short* qtp  = (unsigned short*)(ws + QT);
  unsigned short* ctx  = (unsigned short*)(ws + CTX);
  unsigned short* mqk  = (unsigned short*)(ws + MQK);
  unsigned short* mvp  = (unsigned short*)(ws + MVP);
  float* bqk = (float*)(ws + BQK);
  float* bvp = (float*)(ws + BVP);
  unsigned short* wqkvs = (unsigned short*)(ws + WQKVS);
  float* bqkvs = (float*)(ws + BQKVS);
  unsigned short* wps = (unsigned short*)(ws + WPS);
  unsigned short* w1t = (unsigned short*)(ws + W1T), *w2t = (unsigned short*)(ws + W2T);
  unsigned short* qn_c = (unsigned short*)(ws + QN_C);
  float* spe   = (float*)(ws + SPE);
  unsigned short* part1 = (unsigned short*)(ws + PART1);
  float* pstat = (float*)(ws + PSTAT);
  float* prb   = (float*)(ws + PRB);
  float* s2a   = (float*)(ws + S2A);
  float*          x1   = (float*)(ws + X1);
  unsigned short* qn_s = (unsigned short*)(ws + QN_S);
  unsigned short* vn_s = (unsigned short*)(ws + VN_S);
  float* qkv_s = (float*)(ws + QKV_S);
  unsigned short* s_o  = (unsigned short*)(ws + S_O);
  float*          x2   = (float*)(ws + X2);
  unsigned short* ffn_n = (unsigned short*)(ws + FFN);
  unsigned short* h1    = (unsigned short*)(ws + H1);

  // 1. all prep in one launch
  prep_all<<<6018, 256, 0, stream>>>(
      Wq_s, Wk_s, Wv_s, Wp_s, W1, W2, Wq_c, Wk_c, Wv_c, Wp_c,
      bq_s, bv_s, bq_c, bv_c, bp_c, pooled, cross_pe, ln_qc_g, ln_qc_b,
      wqkvs, wps, w1t, w2t, mqk, mvp, bqk, bvp, bqkvs, spe, qn_c);

  // 2. q~ = qn_c @ Mqk^T + bqk  -> [BW,2048] bf16
  gemm_bt<<<(BW_ / 64) * (2048 / 64), 256, 0, stream>>>(qn_c, mqk, BW_, 2048, 256,
      bqk, nullptr, nullptr, qtp, 0);

  // 3-5. fused cross attention (no kn/vn materialization)
  xattn_score<<<768, 704, 0, stream>>>(features, qtp, ln_kv_g, cross_pe, part1, pstat);
  xattn_sm<<<BW_, 256, 0, stream>>>(part1, pstat, qtp, spe, ln_kv_g, ln_kv_b, prb, s2a);
  xattn_ctx<<<768, 704, 0, stream>>>(features, prb, s2a, ln_vc_g, ln_vc_b, ctx);

  // 6. x1 = ctx @ Mvp^T + bvp + pooled
  gemm_bt<<<(BW_ / 64) * (C_ / 64), 256, 0, stream>>>(ctx, mvp, BW_, C_, 2048,
      bvp, pooled, x1, nullptr, 0);

  // 7. qn_s = LN(x1+self_pe), vn_s = LN(x1)
  ln_dual<<<BW_, 256, 0, stream>>>(x1, self_pe, ln_qs_g, ln_qs_b,
                                   ln_vs_g, ln_vs_b, qn_s, vn_s);

  // 8. q|k from qn_s -> qkv_s cols [0,512); v from vn_s -> cols [512,768)
  gemm_bt_st<<<(BW_ / 64) * (512 / 64), 256, 0, stream>>>(qn_s, wqkvs, BW_, 512, 256,
      768, bqkvs, qkv_s);
  gemm_bt_st<<<(BW_ / 64) * (256 / 64), 256, 0, stream>>>(vn_s, wqkvs + 131072, BW_, 256, 256,
      768, bqkvs + 512, qkv_s + 512);

  // 9. self attention core
  self_attn3<<<B_ * 8, 192, 0, stream>>>(qkv_s, s_o);

  // 10. x2 = s_o @ Wp_s + bp_s + x1
  gemm_bt<<<(BW_ / 64) * (C_ / 64), 256, 0, stream>>>(s_o, wps, BW_, C_, C_,
      bp_s, x1, x2, nullptr, 0);

  // 11. FFN
  ln_rows<<<BW_, 256, 0, stream>>>(x2, ln_ffn_g, ln_ffn_b, ffn_n);
  gemm_bt<<<(BW_ / 64) * (F_ / 64), 256, 0, stream>>>(ffn_n, w1t, BW_, F_, C_,
      b1, nullptr, nullptr, h1, 1);
  gemm_bt<<<(BW_ / 64) * (C_ / 64), 256, 0, stream>>>(h1, w2t, BW_, C_, F_,
      b2, x2, outp, nullptr, 0);
}

// Round 8
// 556.974 us; speedup vs baseline: 1.6161x; 1.0432x over previous
//
#include <hip/hip_runtime.h>
#include <math.h>

// Problem dims
#define B_   48
#define W_   88
#define C_   256
#define H_   32
#define F_   1024
#define BW_  (B_ * W_)        // 4224
#define BWH_ (B_ * W_ * H_)   // 135168
#define HW_  (H_ * W_)        // 2816

typedef float  f32x4  __attribute__((ext_vector_type(4)));
typedef __bf16 bf16x8 __attribute__((ext_vector_type(8)));

__device__ __forceinline__ unsigned short f2bf(float f) {
  union { float f; unsigned int u; } v; v.f = f;
  unsigned int r = v.u + 0x7FFFu + ((v.u >> 16) & 1u);  // RNE
  return (unsigned short)(r >> 16);
}
__device__ __forceinline__ float bf2f(unsigned short h) {
  union { unsigned int u; float f; } v; v.u = ((unsigned int)h) << 16;
  return v.f;
}
__device__ __forceinline__ unsigned int pack2(float a, float b) {
  return (unsigned int)f2bf(a) | ((unsigned int)f2bf(b) << 16);
}

// ---------------------------------------------------------------------------
// prep_all: every weight-prep step in ONE launch (unchanged from R7).
// ---------------------------------------------------------------------------
__global__ __launch_bounds__(256) void prep_all(
    const float* __restrict__ Wq_s, const float* __restrict__ Wk_s,
    const float* __restrict__ Wv_s, const float* __restrict__ Wp_s,
    const float* __restrict__ W1, const float* __restrict__ W2,
    const float* __restrict__ Wq_c, const float* __restrict__ Wk_c,
    const float* __restrict__ Wv_c, const float* __restrict__ Wp_c,
    const float* __restrict__ bq_s, const float* __restrict__ bv_s,
    const float* __restrict__ bq_c, const float* __restrict__ bv_c,
    const float* __restrict__ bp_c,
    const float* __restrict__ pooled, const float* __restrict__ cross_pe,
    const float* __restrict__ ln_qc_g, const float* __restrict__ ln_qc_b,
    unsigned short* __restrict__ wqkvs, unsigned short* __restrict__ wps,
    unsigned short* __restrict__ w1t, unsigned short* __restrict__ w2t,
    unsigned short* __restrict__ mqk, unsigned short* __restrict__ mvp,
    float* __restrict__ bqk, float* __restrict__ bvp,
    float* __restrict__ bqkvs, float* __restrict__ spe,
    unsigned short* __restrict__ qn_c) {
  __shared__ float smem[256 * 33 + 4 * 33];
  int blk = blockIdx.x, t = threadIdx.x;

  if (blk < 768) {
    const float* src; unsigned short* dst; int Cc, R, tile;
    if (blk < 64)       { src = Wq_s; dst = wqkvs;          Cc = 256;  R = 256;  tile = blk; }
    else if (blk < 128) { src = Wk_s; dst = wqkvs + 65536;  Cc = 256;  R = 256;  tile = blk - 64; }
    else if (blk < 192) { src = Wv_s; dst = wqkvs + 131072; Cc = 256;  R = 256;  tile = blk - 128; }
    else if (blk < 256) { src = Wp_s; dst = wps;            Cc = 256;  R = 256;  tile = blk - 192; }
    else if (blk < 512) { src = W1;   dst = w1t;            Cc = 1024; R = 256;  tile = blk - 256; }
    else                { src = W2;   dst = w2t;            Cc = 256;  R = 1024; tile = blk - 512; }
    int tcn = Cc >> 5;
    int tr = tile / tcn, tc = tile % tcn;
    float (*lds)[33] = (float(*)[33])smem;
    int r = t >> 3, c4 = (t & 7) * 4;
    float4 v = *(const float4*)(src + (size_t)(tr * 32 + r) * Cc + tc * 32 + c4);
    lds[r][c4 + 0] = v.x; lds[r][c4 + 1] = v.y; lds[r][c4 + 2] = v.z; lds[r][c4 + 3] = v.w;
    __syncthreads();
    int rd = t >> 3, cd4 = (t & 7) * 4;
    uint2 u;
    u.x = pack2(lds[cd4 + 0][rd], lds[cd4 + 1][rd]);
    u.y = pack2(lds[cd4 + 2][rd], lds[cd4 + 3][rd]);
    *(uint2*)(dst + (size_t)(tc * 32 + rd) * R + tr * 32 + cd4) = u;
  } else if (blk < 1280) {
    int lb = blk - 768;
    int h = lb >> 6, cb = lb & 63;
    float (*wq)[33] = (float(*)[33])smem;
    float (*wk)[33] = (float(*)[33])(smem + 256 * 33);
#pragma unroll
    for (int p = 0; p < 8; p++) {
      int dp = (t >> 3) + 32 * p, d4 = (t & 7) * 4;
      float4 v = *(const float4*)(Wq_c + (size_t)dp * 256 + 32 * h + d4);
      wq[dp][d4 + 0] = v.x; wq[dp][d4 + 1] = v.y; wq[dp][d4 + 2] = v.z; wq[dp][d4 + 3] = v.w;
    }
    if (t < 128) {
      int c_l = t >> 5, dd = t & 31;
      wk[c_l][dd] = Wk_c[(size_t)(cb * 4 + c_l) * 256 + 32 * h + dd];
    }
    __syncthreads();
    const float scale = 0.17677669529663689f;
    int c_l = t >> 6, ln = t & 63;
    int n = 256 * h + cb * 4 + c_l;
#pragma unroll
    for (int j = 0; j < 4; j++) {
      int dp = ln + 64 * j;
      float acc = 0.f;
#pragma unroll
      for (int dd = 0; dd < 32; dd++) acc += wq[dp][dd] * wk[c_l][dd];
      mqk[(size_t)n * 256 + dp] = f2bf(acc * scale);
    }
    if (ln == 0) {
      float bb = 0.f;
#pragma unroll
      for (int dd = 0; dd < 32; dd++) bb += bq_c[32 * h + dd] * wk[c_l][dd];
      bqk[n] = bb * scale;
    }
  } else if (blk < 1792) {
    int lb = blk - 1280;
    int h = lb >> 6, db = lb & 63;
    float (*wv)[33] = (float(*)[33])smem;
    float (*wp)[33] = (float(*)[33])(smem + 256 * 33);
#pragma unroll
    for (int p = 0; p < 8; p++) {
      int c = (t >> 3) + 32 * p, d4 = (t & 7) * 4;
      float4 v = *(const float4*)(Wv_c + (size_t)c * 256 + 32 * h + d4);
      wv[c][d4 + 0] = v.x; wv[c][d4 + 1] = v.y; wv[c][d4 + 2] = v.z; wv[c][d4 + 3] = v.w;
    }
    if (t < 128) {
      int d_l = t >> 5, dd = t & 31;
      wp[d_l][dd] = Wp_c[(size_t)(32 * h + dd) * 256 + db * 4 + d_l];
    }
    __syncthreads();
    int d_l = t >> 6, ln = t & 63;
    int d = db * 4 + d_l;
#pragma unroll
    for (int j = 0; j < 4; j++) {
      int c = ln + 64 * j;
      float acc = 0.f;
#pragma unroll
      for (int dd = 0; dd < 32; dd++) acc += wv[c][dd] * wp[d_l][dd];
      mvp[(size_t)d * 2048 + 256 * h + c] = f2bf(acc);
    }
  } else if (blk == 1792) {
    float acc = bp_c[t];
    for (int dp = 0; dp < 256; dp++) acc += bv_c[dp] * Wp_c[(size_t)dp * 256 + t];
    bvp[t] = acc;
    bqkvs[t] = bq_s[t]; bqkvs[256 + t] = 0.f; bqkvs[512 + t] = bv_s[t];
  } else if (blk == 1793) {
    int j = t >> 3, cp = t & 7;
    float sp = 0.f, sp2 = 0.f;
    for (int i = 0; i < 32; i++) {
      float v = cross_pe[j * 256 + cp * 32 + i];
      sp += v; sp2 += v * v;
    }
    smem[j * 8 + cp] = sp; smem[256 + j * 8 + cp] = sp2;
    __syncthreads();
    if (t < 32) {
      float a = 0.f, a2 = 0.f;
      for (int i = 0; i < 8; i++) { a += smem[t * 8 + i]; a2 += smem[256 + t * 8 + i]; }
      spe[t] = a; spe[32 + t] = a2;
    }
  } else {
    int row = blk - 1794, c = t;
    float v = pooled[(size_t)row * C_ + c];
    float s1 = v, s2 = v * v;
#pragma unroll
    for (int m = 32; m > 0; m >>= 1) {
      s1 += __shfl_xor(s1, m, 64); s2 += __shfl_xor(s2, m, 64);
    }
    float* red = smem;
    int wave = c >> 6;
    if ((c & 63) == 0) { red[wave] = s1; red[4 + wave] = s2; }
    __syncthreads();
    s1 = red[0] + red[1] + red[2] + red[3];
    s2 = red[4] + red[5] + red[6] + red[7];
    float mu = s1 * (1.f / C_);
    float rs = rsqrtf(s2 * (1.f / C_) - mu * mu + 1e-5f);
    qn_c[(size_t)row * C_ + c] = f2bf((v - mu) * rs * ln_qc_g[c] + ln_qc_b[c]);
  }
}

// ---------------------------------------------------------------------------
// xfuse: ENTIRE cross-attention in one kernel. Block = (b, w-oct), 528 blocks,
// 256 threads. All partials block-local (no part1/pstat). Two passes over
// features c-chunks staged in LDS (pass2 L3-warm). Thread roles:
//   (w = t>>5, h = (t>>2)&7, jo = t&3)  for a1/softmax/ctx (j-oct = jo*8..)
//   (ws = t>>5, js = t&31)              for per-(j,w) LN stats
// LDS kvl [c][w][j] with c-stride 258: a1/stats reads conflict-free,
// pass2 reads 2-way (free), staging ~2-way.
// ---------------------------------------------------------------------------
#define CSTR 258
__global__ __launch_bounds__(256) void xfuse(
    const float* __restrict__ features, const unsigned short* __restrict__ qt,
    const float* __restrict__ gk, const float* __restrict__ bk,
    const float* __restrict__ cross_pe, const float* __restrict__ spe,
    const float* __restrict__ gv, const float* __restrict__ bvv,
    unsigned short* __restrict__ ctx) {
  int b = blockIdx.x / 11, wo = blockIdx.x % 11;
  int t = threadIdx.x;
  int w = t >> 5, h = (t >> 2) & 7, jo = t & 3;
  int ws = t >> 5, js = t & 31;
  int gw = wo * 8 + w;

  __shared__ __attribute__((aligned(16))) unsigned short kvl[32 * CSTR];
  __shared__ float pel[32 * 32];     // [c][j]
  __shared__ float qgl[8 * 264];     // [w][h*33 + c]
  __shared__ float psl[8 * 264];     // [w][h*33 + j]
  __shared__ float mukl[8][32], rskl[8][32], mul[8][32], rsl[8][32];
  __shared__ float s2hl[8][8];

  float a1q[8] = {0.f, 0.f, 0.f, 0.f, 0.f, 0.f, 0.f, 0.f};
  float st1 = 0.f, st2 = 0.f, scr = 0.f;
  float a3p = 0.f, a4p = 0.f;

  // ---------------- pass 1: stats + score partials ----------------
  for (int ch = 0; ch < 8; ch++) {
    // stage kv chunk: (c 0..31, j 0..31, w8) -> kvl[c*CSTR + w*32 + j] bf16
#pragma unroll
    for (int k = 0; k < 4; k++) {
      int s = t + k * 256;
      int c = s >> 5, j = s & 31;
      const float* src = features + ((size_t)(b * 256 + ch * 32 + c)) * HW_ + j * 88 + wo * 8;
      float4 v0 = *(const float4*)(src);
      float4 v1 = *(const float4*)(src + 4);
      unsigned short* dst = &kvl[c * CSTR + j];
      dst[0]   = f2bf(v0.x); dst[32]  = f2bf(v0.y); dst[64]  = f2bf(v0.z); dst[96]  = f2bf(v0.w);
      dst[128] = f2bf(v1.x); dst[160] = f2bf(v1.y); dst[192] = f2bf(v1.z); dst[224] = f2bf(v1.w);
    }
    // stage pe chunk: pel[c*32+j] = pe[j][ch*32+c]
#pragma unroll
    for (int k = 0; k < 4; k++) {
      int s = t + k * 256;
      int c = s >> 5, j = s & 31;
      pel[c * 32 + j] = cross_pe[j * 256 + ch * 32 + c];
    }
    // stage g-scaled q~ + accumulate a3/a4: thread (w,h,jo) owns c-seg jo*8..+8
    {
      int c0 = ch * 32 + jo * 8;
      bf16x8 qv = *(const bf16x8*)(qt + (size_t)(b * 88 + gw) * 2048 + h * 256 + c0);
      float4 g0 = *(const float4*)(gk + c0), g1 = *(const float4*)(gk + c0 + 4);
      float4 b0 = *(const float4*)(bk + c0), b1 = *(const float4*)(bk + c0 + 4);
      float ga[8] = {g0.x, g0.y, g0.z, g0.w, g1.x, g1.y, g1.z, g1.w};
      float ba[8] = {b0.x, b0.y, b0.z, b0.w, b1.x, b1.y, b1.z, b1.w};
#pragma unroll
      for (int i = 0; i < 8; i++) {
        float qf = (float)qv[i];
        qgl[w * 264 + h * 33 + jo * 8 + i] = ga[i] * qf;
        a3p += ba[i] * qf;
        a4p += ga[i] * qf;
      }
    }
    __syncthreads();
    // a1: thread (w,h,jo), j = jo*8+i, sum over chunk c
#pragma unroll 4
    for (int c = 0; c < 32; c++) {
      float gq = qgl[w * 264 + h * 33 + c];
      const unsigned short* kr = &kvl[c * CSTR + w * 32 + jo * 8];
      const float* pr_ = &pel[c * 32 + jo * 8];
#pragma unroll
      for (int i = 0; i < 8; i++)
        a1q[i] += gq * (bf2f(kr[i]) + pr_[i]);
    }
    // stats: thread (ws, js)
#pragma unroll 4
    for (int c = 0; c < 32; c++) {
      float v = bf2f(kvl[c * CSTR + ws * 32 + js]);
      float p = pel[c * 32 + js];
      st1 += v; st2 += v * v; scr += v * p;
    }
    __syncthreads();
  }

  // ---------------- LN constants per (j, w) ----------------
  {
    float mu  = st1 * (1.f / 256.f);
    float rs  = rsqrtf(st2 * (1.f / 256.f) - mu * mu + 1e-5f);
    float muk = (st1 + spe[js]) * (1.f / 256.f);
    float rsk = rsqrtf((st2 + 2.f * scr + spe[32 + js]) * (1.f / 256.f) - muk * muk + 1e-5f);
    mukl[ws][js] = muk; rskl[ws][js] = rsk; mul[ws][js] = mu; rsl[ws][js] = rs;
  }
  // a3/a4 full sums (reduce over jo: lanes ±1, ±2 in-wave)
  a3p += __shfl_xor(a3p, 1, 64); a3p += __shfl_xor(a3p, 2, 64);
  a4p += __shfl_xor(a4p, 1, 64); a4p += __shfl_xor(a4p, 2, 64);
  __syncthreads();

  // ---------------- softmax per (w,h) over 32 j ----------------
  {
    float s8[8];
    float mx = -1e30f;
#pragma unroll
    for (int i = 0; i < 8; i++) {
      int j = jo * 8 + i;
      float rsk = rskl[w][j];
      float s = rsk * a1q[i] + a3p - mukl[w][j] * rsk * a4p;
      s8[i] = s; mx = fmaxf(mx, s);
    }
    mx = fmaxf(mx, __shfl_xor(mx, 1, 64));
    mx = fmaxf(mx, __shfl_xor(mx, 2, 64));
    float sum = 0.f;
#pragma unroll
    for (int i = 0; i < 8; i++) { s8[i] = __expf(s8[i] - mx); sum += s8[i]; }
    sum += __shfl_xor(sum, 1, 64); sum += __shfl_xor(sum, 2, 64);
    float inv = 1.f / sum;
    float sp = 0.f;
#pragma unroll
    for (int i = 0; i < 8; i++) {
      int j = jo * 8 + i;
      float prs = s8[i] * inv * rsl[w][j];
      psl[w * 264 + h * 33 + j] = prs;
      sp += prs * mul[w][j];
    }
    sp += __shfl_xor(sp, 1, 64); sp += __shfl_xor(sp, 2, 64);
    if (jo == 0) s2hl[w][h] = sp;
  }
  __syncthreads();

  // ---------------- pass 2: ctx ----------------
  float S2 = s2hl[w][h];
  for (int ch = 0; ch < 8; ch++) {
#pragma unroll
    for (int k = 0; k < 4; k++) {
      int s = t + k * 256;
      int c = s >> 5, j = s & 31;
      const float* src = features + ((size_t)(b * 256 + ch * 32 + c)) * HW_ + j * 88 + wo * 8;
      float4 v0 = *(const float4*)(src);
      float4 v1 = *(const float4*)(src + 4);
      unsigned short* dst = &kvl[c * CSTR + j];
      dst[0]   = f2bf(v0.x); dst[32]  = f2bf(v0.y); dst[64]  = f2bf(v0.z); dst[96]  = f2bf(v0.w);
      dst[128] = f2bf(v1.x); dst[160] = f2bf(v1.y); dst[192] = f2bf(v1.z); dst[224] = f2bf(v1.w);
    }
    __syncthreads();
    float U[8] = {0.f, 0.f, 0.f, 0.f, 0.f, 0.f, 0.f, 0.f};
    const float* pp = &psl[w * 264 + h * 33];
#pragma unroll 4
    for (int j = 0; j < 32; j++) {
      float p = pp[j];
      const unsigned short* kr = &kvl[jo * 8 * CSTR + w * 32 + j];
#pragma unroll
      for (int i = 0; i < 8; i++)
        U[i] += p * bf2f(kr[i * CSTR]);
    }
    int c0 = ch * 32 + jo * 8;
    float4 gv0 = *(const float4*)(gv + c0), gv1 = *(const float4*)(gv + c0 + 4);
    float4 bv0 = *(const float4*)(bvv + c0), bv1 = *(const float4*)(bvv + c0 + 4);
    float gva[8] = {gv0.x, gv0.y, gv0.z, gv0.w, gv1.x, gv1.y, gv1.z, gv1.w};
    float bva[8] = {bv0.x, bv0.y, bv0.z, bv0.w, bv1.x, bv1.y, bv1.z, bv1.w};
    unsigned short pk[8];
#pragma unroll
    for (int i = 0; i < 8; i++)
      pk[i] = f2bf(gva[i] * (U[i] - S2) + bva[i]);
    *(uint4*)(ctx + (size_t)(b * 88 + gw) * 2048 + h * 256 + c0) = *(uint4*)pk;
    if (ch < 7) __syncthreads();
  }
}

// ---------------------------------------------------------------------------
// Row LayerNorm: x f32 [rows, C_] -> bf16 out
// ---------------------------------------------------------------------------
__global__ __launch_bounds__(256) void ln_rows(
    const float* __restrict__ x,
    const float* __restrict__ g, const float* __restrict__ bta,
    unsigned short* __restrict__ out) {
  int row = blockIdx.x, c = threadIdx.x;
  float v = x[(size_t)row * C_ + c];
  float s1 = v, s2 = v * v;
#pragma unroll
  for (int m = 32; m > 0; m >>= 1) {
    s1 += __shfl_xor(s1, m, 64);
    s2 += __shfl_xor(s2, m, 64);
  }
  __shared__ float red[8];
  int wave = c >> 6;
  if ((c & 63) == 0) { red[wave] = s1; red[4 + wave] = s2; }
  __syncthreads();
  s1 = red[0] + red[1] + red[2] + red[3];
  s2 = red[4] + red[5] + red[6] + red[7];
  float mu = s1 * (1.f / C_);
  float rs = rsqrtf(s2 * (1.f / C_) - mu * mu + 1e-5f);
  out[(size_t)row * C_ + c] = f2bf((v - mu) * rs * g[c] + bta[c]);
}

// ---------------------------------------------------------------------------
// ln_dual: out1 = LN(x+pe)*g1+b1, out2 = LN(x)*g2+b2. One read of x.
// ---------------------------------------------------------------------------
__global__ __launch_bounds__(256) void ln_dual(
    const float* __restrict__ x, const float* __restrict__ pe,
    const float* __restrict__ g1, const float* __restrict__ b1a,
    const float* __restrict__ g2, const float* __restrict__ b2a,
    unsigned short* __restrict__ out1, unsigned short* __restrict__ out2) {
  int row = blockIdx.x, c = threadIdx.x;
  float v = x[(size_t)row * C_ + c];
  float vp = v + pe[(size_t)(row % 88) * C_ + c];
  float s1 = v, s2 = v * v, t1 = vp, t2 = vp * vp;
#pragma unroll
  for (int m = 32; m > 0; m >>= 1) {
    s1 += __shfl_xor(s1, m, 64); s2 += __shfl_xor(s2, m, 64);
    t1 += __shfl_xor(t1, m, 64); t2 += __shfl_xor(t2, m, 64);
  }
  __shared__ float red[16];
  int wave = c >> 6;
  if ((c & 63) == 0) {
    red[wave] = s1; red[4 + wave] = s2; red[8 + wave] = t1; red[12 + wave] = t2;
  }
  __syncthreads();
  s1 = red[0] + red[1] + red[2] + red[3];
  s2 = red[4] + red[5] + red[6] + red[7];
  t1 = red[8] + red[9] + red[10] + red[11];
  t2 = red[12] + red[13] + red[14] + red[15];
  float mu = s1 * (1.f / C_), rs = rsqrtf(s2 * (1.f / C_) - mu * mu + 1e-5f);
  float mup = t1 * (1.f / C_), rsp = rsqrtf(t2 * (1.f / C_) - mup * mup + 1e-5f);
  out1[(size_t)row * C_ + c] = f2bf((vp - mup) * rsp * g1[c] + b1a[c]);
  out2[(size_t)row * C_ + c] = f2bf((v - mu) * rs * g2[c] + b2a[c]);
}

// ---------------------------------------------------------------------------
// GEMM: out[M,N] = A[M,K](bf16) @ Bt[N,K](bf16)^T, fp32 acc, reg double-buffer.
// ---------------------------------------------------------------------------
__global__ __launch_bounds__(256) void gemm_bt(
    const unsigned short* __restrict__ A, const unsigned short* __restrict__ Bt,
    int M, int N, int K,
    const float* __restrict__ bias, const float* __restrict__ resid,
    float* __restrict__ outF, unsigned short* __restrict__ outB, int act_gelu) {
  __shared__ __attribute__((aligned(16))) unsigned short As[64][32];
  __shared__ __attribute__((aligned(16))) unsigned short Bs[64][32];
  const int tiles_n = N >> 6;
  const int bm = blockIdx.x / tiles_n;
  const int bn = blockIdx.x % tiles_n;
  const int tid = threadIdx.x;
  const int wave = tid >> 6, lane = tid & 63;
  const int quad = lane >> 4, lr = lane & 15;
  const int wm = (wave >> 1) << 5, wn = (wave & 1) << 5;
  const int lrow = tid >> 2;
  const int lcol = (tid & 3) << 3;
  const size_t a_base = (size_t)(bm * 64 + lrow) * K + lcol;
  const size_t b_base = (size_t)(bn * 64 + lrow) * K + lcol;
  f32x4 acc[2][2] = {};
  uint4 areg = *(const uint4*)(A + a_base);
  uint4 breg = *(const uint4*)(Bt + b_base);
  for (int k0 = 0; k0 < K; k0 += 32) {
    *(uint4*)&As[lrow][lcol] = areg;
    *(uint4*)&Bs[lrow][lcol] = breg;
    __syncthreads();
    if (k0 + 32 < K) {
      areg = *(const uint4*)(A + a_base + k0 + 32);
      breg = *(const uint4*)(Bt + b_base + k0 + 32);
    }
    bf16x8 af0 = *(const bf16x8*)&As[wm + lr][quad << 3];
    bf16x8 af1 = *(const bf16x8*)&As[wm + 16 + lr][quad << 3];
    bf16x8 bf0 = *(const bf16x8*)&Bs[wn + lr][quad << 3];
    bf16x8 bf1 = *(const bf16x8*)&Bs[wn + 16 + lr][quad << 3];
    acc[0][0] = __builtin_amdgcn_mfma_f32_16x16x32_bf16(af0, bf0, acc[0][0], 0, 0, 0);
    acc[0][1] = __builtin_amdgcn_mfma_f32_16x16x32_bf16(af0, bf1, acc[0][1], 0, 0, 0);
    acc[1][0] = __builtin_amdgcn_mfma_f32_16x16x32_bf16(af1, bf0, acc[1][0], 0, 0, 0);
    acc[1][1] = __builtin_amdgcn_mfma_f32_16x16x32_bf16(af1, bf1, acc[1][1], 0, 0, 0);
    __syncthreads();
  }
#pragma unroll
  for (int i = 0; i < 2; i++)
#pragma unroll
    for (int j = 0; j < 2; j++)
#pragma unroll
      for (int rr = 0; rr < 4; rr++) {
        int row = bm * 64 + wm + i * 16 + quad * 4 + rr;
        int col = bn * 64 + wn + j * 16 + lr;
        float val = acc[i][j][rr];
        if (bias) val += bias[col];
        if (act_gelu) val = 0.5f * val * (1.f + erff(val * 0.70710678118654752f));
        if (resid) val += resid[(size_t)row * N + col];
        if (outF) outF[(size_t)row * N + col] = val;
        else outB[(size_t)row * N + col] = f2bf(val);
      }
}

// ---------------------------------------------------------------------------
// gemm_bt_st: like gemm_bt but writes f32 with row stride ldc (+bias).
// ---------------------------------------------------------------------------
__global__ __launch_bounds__(256) void gemm_bt_st(
    const unsigned short* __restrict__ A, const unsigned short* __restrict__ Bt,
    int M, int N, int K, int ldc,
    const float* __restrict__ bias, float* __restrict__ outF) {
  __shared__ __attribute__((aligned(16))) unsigned short As[64][32];
  __shared__ __attribute__((aligned(16))) unsigned short Bs[64][32];
  const int tiles_n = N >> 6;
  const int bm = blockIdx.x / tiles_n;
  const int bn = blockIdx.x % tiles_n;
  const int tid = threadIdx.x;
  const int wave = tid >> 6, lane = tid & 63;
  const int quad = lane >> 4, lr = lane & 15;
  const int wm = (wave >> 1) << 5, wn = (wave & 1) << 5;
  const int lrow = tid >> 2;
  const int lcol = (tid & 3) << 3;
  const size_t a_base = (size_t)(bm * 64 + lrow) * K + lcol;
  const size_t b_base = (size_t)(bn * 64 + lrow) * K + lcol;
  f32x4 acc[2][2] = {};
  uint4 areg = *(const uint4*)(A + a_base);
  uint4 breg = *(const uint4*)(Bt + b_base);
  for (int k0 = 0; k0 < K; k0 += 32) {
    *(uint4*)&As[lrow][lcol] = areg;
    *(uint4*)&Bs[lrow][lcol] = breg;
    __syncthreads();
    if (k0 + 32 < K) {
      areg = *(const uint4*)(A + a_base + k0 + 32);
      breg = *(const uint4*)(Bt + b_base + k0 + 32);
    }
    bf16x8 af0 = *(const bf16x8*)&As[wm + lr][quad << 3];
    bf16x8 af1 = *(const bf16x8*)&As[wm + 16 + lr][quad << 3];
    bf16x8 bf0 = *(const bf16x8*)&Bs[wn + lr][quad << 3];
    bf16x8 bf1 = *(const bf16x8*)&Bs[wn + 16 + lr][quad << 3];
    acc[0][0] = __builtin_amdgcn_mfma_f32_16x16x32_bf16(af0, bf0, acc[0][0], 0, 0, 0);
    acc[0][1] = __builtin_amdgcn_mfma_f32_16x16x32_bf16(af0, bf1, acc[0][1], 0, 0, 0);
    acc[1][0] = __builtin_amdgcn_mfma_f32_16x16x32_bf16(af1, bf0, acc[1][0], 0, 0, 0);
    acc[1][1] = __builtin_amdgcn_mfma_f32_16x16x32_bf16(af1, bf1, acc[1][1], 0, 0, 0);
    __syncthreads();
  }
#pragma unroll
  for (int i = 0; i < 2; i++)
#pragma unroll
    for (int j = 0; j < 2; j++)
#pragma unroll
      for (int rr = 0; rr < 4; rr++) {
        int row = bm * 64 + wm + i * 16 + quad * 4 + rr;
        int col = bn * 64 + wn + j * 16 + lr;
        outF[(size_t)row * ldc + col] = acc[i][j][rr] + bias[col];
      }
}

// ---------------------------------------------------------------------------
// self_attn3: block=(b,h), 192 threads: pair (r=t>>1, dh=t&1) per query row.
// ---------------------------------------------------------------------------
__global__ __launch_bounds__(192) void self_attn3(
    const float* __restrict__ qkv, unsigned short* __restrict__ out) {
  int b = blockIdx.x >> 3;
  int h = blockIdx.x & 7;
  int t = threadIdx.x;
  __shared__ float kl[88][33];
  __shared__ float vl[88][33];
  for (int i = t; i < 704; i += 192) {
    int m = i >> 3, d4 = (i & 7) << 2;
    float4 kv4 = *(const float4*)(qkv + (size_t)(b * 88 + m) * 768 + 256 + h * 32 + d4);
    float4 vv4 = *(const float4*)(qkv + (size_t)(b * 88 + m) * 768 + 512 + h * 32 + d4);
    kl[m][d4 + 0] = kv4.x; kl[m][d4 + 1] = kv4.y; kl[m][d4 + 2] = kv4.z; kl[m][d4 + 3] = kv4.w;
    vl[m][d4 + 0] = vv4.x; vl[m][d4 + 1] = vv4.y; vl[m][d4 + 2] = vv4.z; vl[m][d4 + 3] = vv4.w;
  }
  __syncthreads();
  int r = t >> 1, dh = t & 1;
  if (r < 88) {
    const float* qrow = qkv + (size_t)(b * 88 + r) * 768 + h * 32;
    float qr[32];
#pragma unroll
    for (int g = 0; g < 8; g++) {
      float4 q4 = *(const float4*)(qrow + g * 4);
      qr[g * 4 + 0] = q4.x; qr[g * 4 + 1] = q4.y; qr[g * 4 + 2] = q4.z; qr[g * 4 + 3] = q4.w;
    }
    float sreg[44];
    float mx = -1e30f;
    int m0 = dh * 44;
    for (int mi = 0; mi < 44; mi++) {
      const float* krow = kl[m0 + mi];
      float s = 0.f;
#pragma unroll
      for (int d = 0; d < 32; d++) s += qr[d] * krow[d];
      s *= 0.17677669529663689f;
      sreg[mi] = s;
      mx = fmaxf(mx, s);
    }
    mx = fmaxf(mx, __shfl_xor(mx, 1, 64));
    float sum = 0.f;
    for (int mi = 0; mi < 44; mi++) { float e = __expf(sreg[mi] - mx); sreg[mi] = e; sum += e; }
    sum += __shfl_xor(sum, 1, 64);
    float inv = 1.f / sum;
    float o[32];
#pragma unroll
    for (int d = 0; d < 32; d++) o[d] = 0.f;
    for (int mi = 0; mi < 44; mi++) {
      float p = sreg[mi] * inv;
      const float* vrow = vl[m0 + mi];
#pragma unroll
      for (int d = 0; d < 32; d++) o[d] += p * vrow[d];
    }
#pragma unroll
    for (int d = 0; d < 32; d++) o[d] += __shfl_xor(o[d], 1, 64);
    unsigned short* orow = out + (size_t)(b * 88 + r) * 256 + h * 32 + dh * 16;
    uint4 u0, u1;
    int d0 = dh * 16;
    u0.x = pack2(o[d0 + 0], o[d0 + 1]);  u0.y = pack2(o[d0 + 2], o[d0 + 3]);
    u0.z = pack2(o[d0 + 4], o[d0 + 5]);  u0.w = pack2(o[d0 + 6], o[d0 + 7]);
    u1.x = pack2(o[d0 + 8], o[d0 + 9]);  u1.y = pack2(o[d0 + 10], o[d0 + 11]);
    u1.z = pack2(o[d0 + 12], o[d0 + 13]); u1.w = pack2(o[d0 + 14], o[d0 + 15]);
    *(uint4*)(orow) = u0;
    *(uint4*)(orow + 8) = u1;
  }
}

// ---------------------------------------------------------------------------
extern "C" void kernel_launch(void* const* d_in, const int* in_sizes, int n_in,
                              void* d_out, int out_size, void* d_ws, size_t ws_size,
                              hipStream_t stream) {
  (void)in_sizes; (void)n_in; (void)out_size; (void)ws_size;
  const float* pooled   = (const float*)d_in[0];
  const float* features = (const float*)d_in[1];
  const float* self_pe  = (const float*)d_in[2];
  const float* cross_pe = (const float*)d_in[3];
  const float* ln_qs_g = (const float*)d_in[4],  *ln_qs_b = (const float*)d_in[5];
  const float* ln_vs_g = (const float*)d_in[6],  *ln_vs_b = (const float*)d_in[7];
  const float* ln_qc_g = (const float*)d_in[8],  *ln_qc_b = (const float*)d_in[9];
  const float* ln_kv_g = (const float*)d_in[10], *ln_kv_b = (const float*)d_in[11];
  const float* ln_vc_g = (const float*)d_in[12], *ln_vc_b = (const float*)d_in[13];
  const float* ln_ffn_g = (const float*)d_in[14], *ln_ffn_b = (const float*)d_in[15];
  const float* Wq_s = (const float*)d_in[16], *Wk_s = (const float*)d_in[17];
  const float* Wv_s = (const float*)d_in[18], *Wp_s = (const float*)d_in[19];
  const float* Wq_c = (const float*)d_in[20], *Wk_c = (const float*)d_in[21];
  const float* Wv_c = (const float*)d_in[22], *Wp_c = (const float*)d_in[23];
  const float* bq_s = (const float*)d_in[24], *bv_s = (const float*)d_in[25];
  const float* bp_s = (const float*)d_in[26], *bq_c = (const float*)d_in[27];
  const float* bv_c = (const float*)d_in[28], *bp_c = (const float*)d_in[29];
  const float* W1 = (const float*)d_in[30], *b1 = (const float*)d_in[31];
  const float* W2 = (const float*)d_in[32], *b2 = (const float*)d_in[33];
  float* outp = (float*)d_out;
  char* ws = (char*)d_ws;

  // ---- workspace layout ----
  size_t off = 0;
  auto alloc = [&](size_t bytes) { size_t o = off; off = (off + bytes + 255) & ~(size_t)255; return o; };
  size_t QT   = alloc((size_t)BW_ * 2048 * 2);
  size_t CTX  = alloc((size_t)BW_ * 2048 * 2);
  size_t MQK  = alloc((size_t)2048 * 256 * 2);
  size_t MVP  = alloc((size_t)256 * 2048 * 2);
  size_t BQK  = alloc(2048 * 4);
  size_t BVP  = alloc(256 * 4);
  size_t WQKVS = alloc((size_t)768 * 256 * 2);
  size_t BQKVS = alloc(768 * 4);
  size_t WPS = alloc(65536 * 2);
  size_t W1T = alloc(262144 * 2), W2T = alloc(262144 * 2);
  size_t QN_C = alloc((size_t)BW_ * C_ * 2);
  size_t SPE  = alloc(64 * 4);
  size_t X1    = alloc((size_t)BW_ * C_ * 4);
  size_t QN_S  = alloc((size_t)BW_ * C_ * 2);
  size_t VN_S  = alloc((size_t)BW_ * C_ * 2);
  size_t QKV_S = alloc((size_t)BW_ * 768 * 4);
  size_t S_O   = alloc((size_t)BW_ * C_ * 2);
  size_t X2    = alloc((size_t)BW_ * C_ * 4);
  size_t FFN   = alloc((size_t)BW_ * C_ * 2);
  size_t H1    = alloc((size_t)BW_ * F_ * 2);

  unsigned short* qtp  = (unsigned short*)(ws + QT);
  unsigned short* ctx  = (unsigned short*)(ws + CTX);
  unsigned short* mqk  = (unsigned short*)(ws + MQK);
  unsigned short* mvp  = (unsigned short*)(ws + MVP);
  float* bqk = (float*)(ws + BQK);
  float* bvp = (float*)(ws + BVP);
  unsigned short* wqkvs = (unsigned short*)(ws + WQKVS);
  float* bqkvs = (float*)(ws + BQKVS);
  unsigned short* wps = (unsigned short*)(ws + WPS);
  unsigned short* w1t = (unsigned short*)(ws + W1T), *w2t = (unsigned short*)(ws + W2T);
  unsigned short* qn_c = (unsigned short*)(ws + QN_C);
  float* spe   = (float*)(ws + SPE);
  float*          x1   = (float*)(ws + X1);
  unsigned short* qn_s = (unsigned short*)(ws + QN_S);
  unsigned short* vn_s = (unsigned short*)(ws + VN_S);
  float* qkv_s = (float*)(ws + QKV_S);
  unsigned short* s_o  = (unsigned short*)(ws + S_O);
  float*          x2   = (float*)(ws + X2);
  unsigned short* ffn_n = (unsigned short*)(ws + FFN);
  unsigned short* h1    = (unsigned short*)(ws + H1);

  // 1. all prep in one launch
  prep_all<<<6018, 256, 0, stream>>>(
      Wq_s, Wk_s, Wv_s, Wp_s, W1, W2, Wq_c, Wk_c, Wv_c, Wp_c,
      bq_s, bv_s, bq_c, bv_c, bp_c, pooled, cross_pe, ln_qc_g, ln_qc_b,
      wqkvs, wps, w1t, w2t, mqk, mvp, bqk, bvp, bqkvs, spe, qn_c);

  // 2. q~ = qn_c @ Mqk^T + bqk  -> [BW,2048] bf16
  gemm_bt<<<(BW_ / 64) * (2048 / 64), 256, 0, stream>>>(qn_c, mqk, BW_, 2048, 256,
      bqk, nullptr, nullptr, qtp, 0);

  // 3. fused cross attention (block-local stats+score+softmax+ctx)
  xfuse<<<B_ * 11, 256, 0, stream>>>(features, qtp, ln_kv_g, ln_kv_b,
      cross_pe, spe, ln_vc_g, ln_vc_b, ctx);

  // 4. x1 = ctx @ Mvp^T + bvp + pooled
  gemm_bt<<<(BW_ / 64) * (C_ / 64), 256, 0, stream>>>(ctx, mvp, BW_, C_, 2048,
      bvp, pooled, x1, nullptr, 0);

  // 5. qn_s = LN(x1+self_pe), vn_s = LN(x1)
  ln_dual<<<BW_, 256, 0, stream>>>(x1, self_pe, ln_qs_g, ln_qs_b,
                                   ln_vs_g, ln_vs_b, qn_s, vn_s);

  // 6. q|k from qn_s -> qkv_s cols [0,512); v from vn_s -> cols [512,768)
  gemm_bt_st<<<(BW_ / 64) * (512 / 64), 256, 0, stream>>>(qn_s, wqkvs, BW_, 512, 256,
      768, bqkvs, qkv_s);
  gemm_bt_st<<<(BW_ / 64) * (256 / 64), 256, 0, stream>>>(vn_s, wqkvs + 131072, BW_, 256, 256,
      768, bqkvs + 512, qkv_s + 512);

  // 7. self attention core
  self_attn3<<<B_ * 8, 192, 0, stream>>>(qkv_s, s_o);

  // 8. x2 = s_o @ Wp_s + bp_s + x1
  gemm_bt<<<(BW_ / 64) * (C_ / 64), 256, 0, stream>>>(s_o, wps, BW_, C_, C_,
      bp_s, x1, x2, nullptr, 0);

  // 9. FFN
  ln_rows<<<BW_, 256, 0, stream>>>(x2, ln_ffn_g, ln_ffn_b, ffn_n);
  gemm_bt<<<(BW_ / 64) * (F_ / 64), 256, 0, stream>>>(ffn_n, w1t, BW_, F_, C_,
      b1, nullptr, nullptr, h1, 1);
  gemm_bt<<<(BW_ / 64) * (C_ / 64), 256, 0, stream>>>(h1, w2t, BW_, C_, F_,
      b2, x2, outp, nullptr, 0);
}